// Round 12
// baseline (544.565 us; speedup 1.0000x reference)
//
#include <hip/hip_runtime.h>
#include <hip/hip_bf16.h>

#define EMB 768
#define NHEADS 8
#define HDIM 96
#define SEQ 2048
#define BATCH 4
#define QKV_COLS 2304
#define PB ((size_t)SEQ * EMB)   // per-batch elements

typedef _Float16 f16;
typedef _Float16 f16x8 __attribute__((ext_vector_type(8)));
typedef float f32x4 __attribute__((ext_vector_type(4)));

__device__ __forceinline__ void gl_lds16(const f16* g, f16* l) {
  __builtin_amdgcn_global_load_lds((const __attribute__((address_space(1))) void*)g,
                                   (__attribute__((address_space(3))) void*)l, 16, 0, 0);
}
__device__ __forceinline__ f32x4 shflx4(f32x4 v, int m) {
  f32x4 r;
  r[0] = __shfl_xor(v[0], m); r[1] = __shfl_xor(v[1], m);
  r[2] = __shfl_xor(v[2], m); r[3] = __shfl_xor(v[3], m);
  return r;
}
__device__ __forceinline__ f32x4 vmax4(f32x4 a, f32x4 b) {
  f32x4 r;
  r[0] = fmaxf(a[0], b[0]); r[1] = fmaxf(a[1], b[1]);
  r[2] = fmaxf(a[2], b[2]); r[3] = fmaxf(a[3], b[3]);
  return r;
}

// ---------------- conversions ----------------
__global__ __launch_bounds__(256) void conv_x8_k(const float* __restrict__ in, size_t in_off,
                                                 f16* __restrict__ out, int n8) {
  int i = blockIdx.x * 256 + threadIdx.x;
  if (i >= n8) return;
  const float4 a = *(const float4*)(in + in_off + (size_t)i * 8);
  const float4 b = *(const float4*)(in + in_off + (size_t)i * 8 + 4);
  f16x8 o;
  o[0] = (f16)a.x; o[1] = (f16)a.y; o[2] = (f16)a.z; o[3] = (f16)a.w;
  o[4] = (f16)b.x; o[5] = (f16)b.y; o[6] = (f16)b.z; o[7] = (f16)b.w;
  *(f16x8*)(out + (size_t)i * 8) = o;
}

// qkv weight: transpose + column-permute. out[col'][r], col' = s*768+h*96+d,
// original col c = h*288+d*3+s. Output-indexed -> coalesced 16B writes.
__global__ __launch_bounds__(256) void wqkv_perm_k(const float* __restrict__ in,
                                                   f16* __restrict__ out) {
  int t = blockIdx.x * 256 + threadIdx.x;          // 0 .. 2304*96-1
  if (t >= QKV_COLS * (EMB / 8)) return;
  const int colp = t / (EMB / 8);
  const int r8 = (t - colp * (EMB / 8)) * 8;
  const int s = colp / 768, rem = colp - s * 768;
  const int h = rem / 96, d = rem - h * 96;
  const int c = h * 288 + d * 3 + s;
  f16x8 o;
#pragma unroll
  for (int i = 0; i < 8; i++) o[i] = (f16)in[(size_t)(r8 + i) * QKV_COLS + c];
  *(f16x8*)(out + (size_t)colp * EMB + r8) = o;
}

// proj weight: plain transpose, output-indexed.
__global__ __launch_bounds__(256) void wproj_t_k(const float* __restrict__ in,
                                                 f16* __restrict__ out) {
  int t = blockIdx.x * 256 + threadIdx.x;          // 0 .. 768*96-1
  if (t >= EMB * (EMB / 8)) return;
  const int cp = t / (EMB / 8);
  const int r8 = (t - cp * (EMB / 8)) * 8;
  f16x8 o;
#pragma unroll
  for (int i = 0; i < 8; i++) o[i] = (f16)in[(size_t)(r8 + i) * EMB + cp];
  *(f16x8*)(out + (size_t)cp * EMB + r8) = o;
}

// bias: permute qkv bias to col' space; copy proj bias.
__global__ __launch_bounds__(256) void bias_perm_k(const float* __restrict__ bq_in,
                                                   float* __restrict__ bq_out,
                                                   const float* __restrict__ bp_in,
                                                   float* __restrict__ bp_out) {
  int i = blockIdx.x * 256 + threadIdx.x;
  if (i < QKV_COLS) {
    const int s = i / 768, rem = i - s * 768;
    const int h = rem / 96, d = rem - h * 96;
    bq_out[i] = bq_in[h * 288 + d * 3 + s];
  }
  if (i < EMB) bp_out[i] = bp_in[i];
}

// ---------------- bt-GEMM: C[M,N] = A[M,K] @ Bt[N,K]^T + bias ----------------
// MODE 0: fp32 store to Cout [M,N], A row-major [M][Kd]
// MODE 1 (permuted qkv): tile_n < 1536 -> QK[row][1536] direct (coalesced);
//                        tile_n >= 1536 -> V: LDS transpose -> Vt[bh][d][n] coalesced
// MODE 2: like MODE 0 but A is head-major [b*8+h][2048][96]; k -> (h = k/96, d = k%96).
//         32-wide k-chunks never straddle heads (96 = 3*32), so h = k0/96 per chunk.
template<int MODE>
__global__ __launch_bounds__(256) void gemm_bt(
    const f16* __restrict__ A, const f16* __restrict__ Bt,
    const float* __restrict__ bias, float* __restrict__ Cout,
    f16* __restrict__ QK, f16* __restrict__ Vt,
    int M, int N, int Kd)
{
  __shared__ f16 smem[MODE == 1 ? 17408 : 8192];   // sA[4096]+sB[4096]; V-epilogue reuses as sT[128][136]
  f16* sA = smem;
  f16* sB = smem + 4096;
  const int tid  = threadIdx.x;
  const int wave = tid >> 6, lane = tid & 63;
  const int quad = lane >> 4, l16 = lane & 15;
  const int tile_m = blockIdx.y * 128, tile_n = blockIdx.x * 128;
  const int wm = (wave >> 1) * 64, wn = (wave & 1) * 64;

  f32x4 acc[4][4];
  for (int i = 0; i < 4; i++)
    for (int j = 0; j < 4; j++)
      acc[i][j] = f32x4{0.f, 0.f, 0.f, 0.f};

  for (int k0 = 0; k0 < Kd; k0 += 32) {
    __syncthreads();
#pragma unroll
    for (int it = 0; it < 2; it++) {
      const int ch  = (it * 4 + wave) * 64 + lane;   // 0..511
      const int row = ch >> 2, c8 = (ch & 3) * 8;
      if (MODE == 2) {
        const int grow = tile_m + row;
        const int bb = grow >> 11, n = grow & 2047;
        const int hh = k0 / 96, d0 = k0 - hh * 96 + c8;
        gl_lds16(A + ((size_t)(bb * NHEADS + hh) * SEQ + n) * HDIM + d0,
                 &sA[(it * 4 + wave) * 512]);
      } else {
        gl_lds16(A + (size_t)(tile_m + row) * Kd + k0 + c8, &sA[(it * 4 + wave) * 512]);
      }
      gl_lds16(Bt + (size_t)(tile_n + row) * Kd + k0 + c8, &sB[(it * 4 + wave) * 512]);
    }
    __syncthreads();

    f16x8 af[4], bfr[4];
    for (int i = 0; i < 4; i++) af[i]  = *(const f16x8*)&sA[(wm + i * 16 + l16) * 32 + quad * 8];
    for (int j = 0; j < 4; j++) bfr[j] = *(const f16x8*)&sB[(wn + j * 16 + l16) * 32 + quad * 8];
    for (int i = 0; i < 4; i++)
      for (int j = 0; j < 4; j++)
        acc[i][j] = __builtin_amdgcn_mfma_f32_16x16x32_f16(af[i], bfr[j], acc[i][j], 0, 0, 0);
  }

  // epilogue: C layout col=lane&15, row=quad*4+reg
  if (MODE == 1 && tile_n >= 1536) {
    // ---- V tile: LDS transpose then coalesced Vt writes ----
    __syncthreads();   // sA/sB dead, safe to overwrite
    f16* sT = smem;    // [128][136]
    for (int j = 0; j < 4; j++) {
      const int cl = wn + j * 16 + l16;
      const float bv = bias[tile_n + cl];
      for (int i = 0; i < 4; i++)
        for (int r = 0; r < 4; r++)
          sT[cl * 136 + wm + i * 16 + quad * 4 + r] = (f16)(acc[i][j][r] + bv);
    }
    __syncthreads();
    const int bb = tile_m >> 11;          // group-local batch
    const int n0 = tile_m & 2047;
#pragma unroll
    for (int l = 0; l < 8; l++) {
      const int cc = l * 256 + tid;       // 0..2047 chunks of 8 f16
      const int rh = cc >> 4, nof = (cc & 15) * 8;
      const int hd = (tile_n - 1536) + rh;
      const int h = hd / 96, d = hd - h * 96;
      f16x8 v = *(const f16x8*)&sT[rh * 136 + nof];
      *(f16x8*)(Vt + ((size_t)(bb * NHEADS + h) * HDIM + d) * SEQ + n0 + nof) = v;
    }
  } else {
    for (int j = 0; j < 4; j++) {
      const int col = tile_n + wn + j * 16 + l16;
      const float bv = bias[col];
      for (int i = 0; i < 4; i++) {
        for (int r = 0; r < 4; r++) {
          const int row = tile_m + wm + i * 16 + quad * 4 + r;
          const float fv = acc[i][j][r] + bv;
          if (MODE != 1) Cout[(size_t)row * N + col] = fv;
          else           QK  [(size_t)row * 1536 + col] = (f16)fv;  // Q cols 0..767, K 768..1535
        }
      }
    }
  }
}

// ---------------- flash attention ----------------
// r12: sP ALIASED into sK -> LDS 64 KB -> 48 KB -> 3 blocks/CU = 12 waves/CU
// (3 waves/SIMD, +50% latency hiding; occupancy was the binding constraint --
// r11 proved staging overlap is worth only ~2 us, so it is traded away).
// Alias safety: sK is read ONLY in QK^T; sP (= first 16 KB of sK) is written/
// read ONLY in softmax/PV; a barrier between the phases certifies all waves
// finished kf reads before any P write. K/V(kt+1) issued after the post-PV
// barrier (all waves done with sP & sV), drained at loop top (synchronous,
// r10-proven flow) via r11's gl_lds + swizzled-source (no ds_writes).
// Compute/softmax/P/PV instruction stream byte-identical to r10/r11 (passed).
//   sK[128][96]: 16B-unit rotation  phys = (u + row) % 12   [src-swizzled stage]
//   sV[96][128]: 16B-unit XOR       phys = u ^ (d & 15)     [src-swizzled stage]
//   sP = sK[0..8191]: 16B-unit XOR  phys = u ^ (row & 7)    (two 64-k halves)
__global__ __launch_bounds__(256, 3) void attn_k(
    const f16* __restrict__ QK, const f16* __restrict__ Vt,
    f16* __restrict__ Out /* [nb*8][2048][96] f16 */, int nbh)
{
  __shared__ f16 sK[128 * 96];
  __shared__ f16 sV[96 * 128];
  f16* sP = sK;                              // alias: 128*64 f16 = 16 KB < 24 KB
  const int tid  = threadIdx.x;
  const int wave = tid >> 6, lane = tid & 63;
  const int quad = lane >> 4, l16 = lane & 15;

  const int bid = blockIdx.x;
  const int xcd = bid & 7, idx = bid >> 3;   // dispatch round-robins XCDs on bid%8
  const int bh  = xcd * (nbh >> 3) + (idx >> 4);
  const int qt  = idx & 15;
  const int b = bh >> 3, h = bh & 7;

  const int wrow = wave * 32;                // this wave's q-row base (32 rows, ti=2)

  const f16* Qb = QK + (size_t)(b * SEQ + qt * 128 + wrow) * 1536 + h * 96;
  const f16* Kb = QK + (size_t)(b * SEQ) * 1536 + 768 + h * 96;
  const f16* Vb = Vt + (size_t)bh * HDIM * SEQ;

  // per-thread pre-swizzled staging source offsets (chunk ck = i*256 + tid):
  //  K: (krow,pu) -> src krow*1536 + ((pu - krow) mod 12)*8 ; dest linear ck*8
  //  V: (vd,pu)   -> src vd*SEQ + (pv ^ (vd&15))*8          ; dest linear ck*8
  int koff[6], voff[6];
#pragma unroll
  for (int i = 0; i < 6; i++) {
    const int ck = i * 256 + tid;
    const int krow = ck / 12, pu = ck - krow * 12;
    const int u = (pu + 12 - krow % 12) % 12;
    koff[i] = krow * 1536 + u * 8;
    const int vd = ck >> 4, pv = ck & 15;
    voff[i] = vd * SEQ + (pv ^ (vd & 15)) * 8;
  }

  f16x8 qf[2][3];
#pragma unroll
  for (int ti = 0; ti < 2; ti++)
#pragma unroll
    for (int kc = 0; kc < 3; kc++)
      qf[ti][kc] = *(const f16x8*)(Qb + (size_t)(ti * 16 + l16) * 1536 + kc * 32 + quad * 8);

  f32x4 oacc[2][6];
#pragma unroll
  for (int ti = 0; ti < 2; ti++)
#pragma unroll
    for (int dj = 0; dj < 6; dj++)
      oacc[ti][dj] = f32x4{0.f, 0.f, 0.f, 0.f};
  f32x4 m_run[2], l_run[2];
#pragma unroll
  for (int ti = 0; ti < 2; ti++) {
    m_run[ti] = f32x4{-1e30f, -1e30f, -1e30f, -1e30f};
    l_run[ti] = f32x4{0.f, 0.f, 0.f, 0.f};
  }

  // prologue: issue K(0), V(0)
#pragma unroll
  for (int i = 0; i < 6; i++) gl_lds16(Kb + koff[i], &sK[(i * 256 + wave * 64) * 8]);
#pragma unroll
  for (int i = 0; i < 6; i++) gl_lds16(Vb + voff[i], &sV[(i * 256 + wave * 64) * 8]);

  const int NT = SEQ / 128;
  for (int kt = 0; kt < NT; kt++) {
    // (a) tiles ready: drain own staging loads, sync all waves
    asm volatile("s_waitcnt vmcnt(0)" ::: "memory");
    __builtin_amdgcn_s_barrier();
    __builtin_amdgcn_sched_barrier(0);

    // ---- QK^T: each kf read feeds both ti MFMAs ----
    f32x4 sacc[2][8];
#pragma unroll
    for (int ti = 0; ti < 2; ti++)
#pragma unroll
      for (int j = 0; j < 8; j++)
        sacc[ti][j] = f32x4{0.f, 0.f, 0.f, 0.f};
#pragma unroll
    for (int kc = 0; kc < 3; kc++) {
#pragma unroll
      for (int j = 0; j < 8; j++) {
        const int krow = j * 16 + l16;
        const f16x8 kf = *(const f16x8*)&sK[krow * 96 + ((kc * 4 + quad + krow) % 12) * 8];
        sacc[0][j] = __builtin_amdgcn_mfma_f32_16x16x32_f16(qf[0][kc], kf, sacc[0][j], 0, 0, 0);
        sacc[1][j] = __builtin_amdgcn_mfma_f32_16x16x32_f16(qf[1][kc], kf, sacc[1][j], 0, 0, 0);
      }
    }

    // (b) alias guard: all waves finished reading sK before P overwrites it
    __builtin_amdgcn_sched_barrier(0);
    __builtin_amdgcn_s_barrier();
    __builtin_amdgcn_sched_barrier(0);

    // ---- stats per ti: max, alpha, rescale ----
    f32x4 rsv[2];
#pragma unroll
    for (int ti = 0; ti < 2; ti++) {
      f32x4 vmx = sacc[ti][0];
#pragma unroll
      for (int j = 1; j < 8; j++) vmx = vmax4(vmx, sacc[ti][j]);
      for (int m = 1; m < 16; m <<= 1) vmx = vmax4(vmx, shflx4(vmx, m));
      const f32x4 nm = vmax4(m_run[ti], vmx);
      f32x4 alpha;
      alpha[0] = __expf(m_run[ti][0] - nm[0]); alpha[1] = __expf(m_run[ti][1] - nm[1]);
      alpha[2] = __expf(m_run[ti][2] - nm[2]); alpha[3] = __expf(m_run[ti][3] - nm[3]);
      m_run[ti] = nm;
      l_run[ti] *= alpha;
      rsv[ti] = f32x4{0.f, 0.f, 0.f, 0.f};
#pragma unroll
      for (int dj = 0; dj < 6; dj++) oacc[ti][dj] *= alpha;
    }

    // ---- two 64-k halves: write P (XOR-swizzled sP=sK) -> PV (vf feeds both ti) ----
#pragma unroll
    for (int c2 = 0; c2 < 2; c2++) {
#pragma unroll
      for (int ti = 0; ti < 2; ti++) {
        const int prow = wrow + ti * 16 + quad * 4;
#pragma unroll
        for (int jl = 0; jl < 4; jl++) {
          const int j = c2 * 4 + jl;
          f32x4 p;
          p[0] = __expf(sacc[ti][j][0] - m_run[ti][0]);
          p[1] = __expf(sacc[ti][j][1] - m_run[ti][1]);
          p[2] = __expf(sacc[ti][j][2] - m_run[ti][2]);
          p[3] = __expf(sacc[ti][j][3] - m_run[ti][3]);
          rsv[ti] += p;
          const int unit = jl * 2 + (l16 >> 3);   // 16B unit of col = jl*16+l16
          const int within = l16 & 7;
#pragma unroll
          for (int rr = 0; rr < 4; rr++) {
            const int row = prow + rr;
            sP[row * 64 + (unit ^ (row & 7)) * 8 + within] = (f16)p[rr];
          }
        }
      }
#pragma unroll
      for (int kc2 = 0; kc2 < 2; kc2++) {
        const f16x8 pf0 = *(const f16x8*)&sP[(wrow + l16) * 64
                                            + ((kc2 * 4 + quad) ^ (l16 & 7)) * 8];
        const f16x8 pf1 = *(const f16x8*)&sP[(wrow + 16 + l16) * 64
                                            + ((kc2 * 4 + quad) ^ (l16 & 7)) * 8];
#pragma unroll
        for (int dj = 0; dj < 6; dj++) {
          const int vph = (c2 * 8 + kc2 * 4 + quad) ^ l16;   // d&15 == l16
          const f16x8 vf = *(const f16x8*)&sV[(dj * 16 + l16) * 128 + vph * 8];
          oacc[0][dj] = __builtin_amdgcn_mfma_f32_16x16x32_f16(pf0, vf, oacc[0][dj], 0, 0, 0);
          oacc[1][dj] = __builtin_amdgcn_mfma_f32_16x16x32_f16(pf1, vf, oacc[1][dj], 0, 0, 0);
        }
      }
    }

    // (c) overwrite guard: all waves done with sP & sV -> safe to stage kt+1
    __builtin_amdgcn_sched_barrier(0);
    __builtin_amdgcn_s_barrier();
    if (kt < NT - 1) {
      const f16* kb = Kb + (size_t)((kt + 1) * 128) * 1536;
      const f16* vb = Vb + (kt + 1) * 128;
#pragma unroll
      for (int i = 0; i < 6; i++) gl_lds16(kb + koff[i], &sK[(i * 256 + wave * 64) * 8]);
#pragma unroll
      for (int i = 0; i < 6; i++) gl_lds16(vb + voff[i], &sV[(i * 256 + wave * 64) * 8]);
    }
    __builtin_amdgcn_sched_barrier(0);

    // ---- finish row sums (registers only; overlaps staging flight) ----
#pragma unroll
    for (int ti = 0; ti < 2; ti++) {
      for (int m = 1; m < 16; m <<= 1) rsv[ti] += shflx4(rsv[ti], m);
      l_run[ti] += rsv[ti];
    }
  }

  const float inv_scale = 0.10206207261596577f;  // 1/sqrt(96), applied AFTER softmax per ref
#pragma unroll
  for (int ti = 0; ti < 2; ti++) {
#pragma unroll
    for (int r = 0; r < 4; r++) {
      const int qrow = qt * 128 + wrow + ti * 16 + quad * 4 + r;
      const float invl = inv_scale / l_run[ti][r];
      const size_t base = ((size_t)bh * SEQ + qrow) * HDIM;   // head-major out
#pragma unroll
      for (int dj = 0; dj < 6; dj++)
        Out[base + dj * 16 + l16] = (f16)(oacc[ti][dj][r] * invl);
    }
  }
}

// ---------------- launch ----------------
extern "C" void kernel_launch(void* const* d_in, const int* in_sizes, int n_in,
                              void* d_out, int out_size, void* d_ws, size_t ws_size,
                              hipStream_t stream) {
  const float* x      = (const float*)d_in[0];
  const float* w_qkv  = (const float*)d_in[1];
  const float* b_qkv  = (const float*)d_in[2];
  const float* w_proj = (const float*)d_in[3];
  const float* b_proj = (const float*)d_in[4];
  float* outF = (float*)d_out;   // fp32 output

  const size_t fixed = 256 + (size_t)QKV_COLS * EMB * 2 + (size_t)EMB * EMB * 2
                     + QKV_COLS * 4 + EMB * 4 + 256;
  const size_t perb = (size_t)4 * PB * 2;  // QK(2) + Vt(1) + attn(1) per batch, in PB units
  int nb = (ws_size >= fixed + 4 * perb) ? 4 : (ws_size >= fixed + 2 * perb) ? 2 : 1;

  char* ws = (char*)d_ws;
  ws += 256;
  f16*   wqkvT  = (f16*)ws;   ws += (size_t)QKV_COLS * EMB * 2;
  f16*   wprojT = (f16*)ws;   ws += (size_t)EMB * EMB * 2;
  float* bq     = (float*)ws; ws += (size_t)QKV_COLS * 4;
  float* bp     = (float*)ws; ws += (size_t)EMB * 4 + 256;
  f16* QK   = (f16*)ws;       ws += (size_t)nb * 2 * PB * 2;   // [nb*2048][1536]
  f16* Vt   = (f16*)ws;       ws += (size_t)nb * PB * 2;       // [nb*8][96][2048]
  f16* attn = (f16*)ws;       ws += (size_t)nb * PB * 2;       // [nb*8][2048][96] head-major

  wqkv_perm_k<<<(QKV_COLS * (EMB / 8) + 255) / 256, 256, 0, stream>>>(w_qkv, wqkvT);
  wproj_t_k<<<(EMB * (EMB / 8) + 255) / 256, 256, 0, stream>>>(w_proj, wprojT);
  bias_perm_k<<<(QKV_COLS + 255) / 256, 256, 0, stream>>>(b_qkv, bq, b_proj, bp);

  for (int outer = 0; outer < BATCH / nb; outer++) {
    const int bbase = outer * nb;
    const size_t goff = (size_t)bbase * PB;
    f16* xg = (f16*)(outF + goff);           // stage f16 x inside fp32 out region (dead before proj)
    const int n8 = (int)((size_t)nb * PB / 8);
    conv_x8_k<<<(n8 + 255) / 256, 256, 0, stream>>>(x, goff, xg, n8);

    dim3 g1(QKV_COLS / 128, nb * SEQ / 128);
    gemm_bt<1><<<g1, 256, 0, stream>>>(xg, wqkvT, bq, nullptr, QK, Vt,
                                       nb * SEQ, QKV_COLS, EMB);

    attn_k<<<dim3(16 * nb * NHEADS), 256, 0, stream>>>(QK, Vt, attn, nb * NHEADS);

    dim3 g3(EMB / 128, nb * SEQ / 128);
    gemm_bt<2><<<g3, 256, 0, stream>>>(attn, wprojT, bp, outF + goff,
                                       nullptr, nullptr,
                                       nb * SEQ, EMB, EMB);
  }
}

// Round 13
// 329.527 us; speedup vs baseline: 1.6526x; 1.6526x over previous
//
#include <hip/hip_runtime.h>
#include <hip/hip_bf16.h>

#define EMB 768
#define NHEADS 8
#define HDIM 96
#define SEQ 2048
#define BATCH 4
#define QKV_COLS 2304
#define PB ((size_t)SEQ * EMB)   // per-batch elements

typedef _Float16 f16;
typedef _Float16 f16x8 __attribute__((ext_vector_type(8)));
typedef float f32x4 __attribute__((ext_vector_type(4)));

__device__ __forceinline__ void gl_lds16(const f16* g, f16* l) {
  __builtin_amdgcn_global_load_lds((const __attribute__((address_space(1))) void*)g,
                                   (__attribute__((address_space(3))) void*)l, 16, 0, 0);
}
__device__ __forceinline__ f32x4 shflx4(f32x4 v, int m) {
  f32x4 r;
  r[0] = __shfl_xor(v[0], m); r[1] = __shfl_xor(v[1], m);
  r[2] = __shfl_xor(v[2], m); r[3] = __shfl_xor(v[3], m);
  return r;
}
__device__ __forceinline__ f32x4 vmax4(f32x4 a, f32x4 b) {
  f32x4 r;
  r[0] = fmaxf(a[0], b[0]); r[1] = fmaxf(a[1], b[1]);
  r[2] = fmaxf(a[2], b[2]); r[3] = fmaxf(a[3], b[3]);
  return r;
}

// ---------------- conversions ----------------
__global__ __launch_bounds__(256) void conv_x8_k(const float* __restrict__ in, size_t in_off,
                                                 f16* __restrict__ out, int n8) {
  int i = blockIdx.x * 256 + threadIdx.x;
  if (i >= n8) return;
  const float4 a = *(const float4*)(in + in_off + (size_t)i * 8);
  const float4 b = *(const float4*)(in + in_off + (size_t)i * 8 + 4);
  f16x8 o;
  o[0] = (f16)a.x; o[1] = (f16)a.y; o[2] = (f16)a.z; o[3] = (f16)a.w;
  o[4] = (f16)b.x; o[5] = (f16)b.y; o[6] = (f16)b.z; o[7] = (f16)b.w;
  *(f16x8*)(out + (size_t)i * 8) = o;
}

// qkv weight: transpose + column-permute. out[col'][r], col' = s*768+h*96+d,
// original col c = h*288+d*3+s. Output-indexed -> coalesced 16B writes.
__global__ __launch_bounds__(256) void wqkv_perm_k(const float* __restrict__ in,
                                                   f16* __restrict__ out) {
  int t = blockIdx.x * 256 + threadIdx.x;          // 0 .. 2304*96-1
  if (t >= QKV_COLS * (EMB / 8)) return;
  const int colp = t / (EMB / 8);
  const int r8 = (t - colp * (EMB / 8)) * 8;
  const int s = colp / 768, rem = colp - s * 768;
  const int h = rem / 96, d = rem - h * 96;
  const int c = h * 288 + d * 3 + s;
  f16x8 o;
#pragma unroll
  for (int i = 0; i < 8; i++) o[i] = (f16)in[(size_t)(r8 + i) * QKV_COLS + c];
  *(f16x8*)(out + (size_t)colp * EMB + r8) = o;
}

// proj weight: plain transpose, output-indexed.
__global__ __launch_bounds__(256) void wproj_t_k(const float* __restrict__ in,
                                                 f16* __restrict__ out) {
  int t = blockIdx.x * 256 + threadIdx.x;          // 0 .. 768*96-1
  if (t >= EMB * (EMB / 8)) return;
  const int cp = t / (EMB / 8);
  const int r8 = (t - cp * (EMB / 8)) * 8;
  f16x8 o;
#pragma unroll
  for (int i = 0; i < 8; i++) o[i] = (f16)in[(size_t)(r8 + i) * EMB + cp];
  *(f16x8*)(out + (size_t)cp * EMB + r8) = o;
}

// bias: permute qkv bias to col' space; copy proj bias.
__global__ __launch_bounds__(256) void bias_perm_k(const float* __restrict__ bq_in,
                                                   float* __restrict__ bq_out,
                                                   const float* __restrict__ bp_in,
                                                   float* __restrict__ bp_out) {
  int i = blockIdx.x * 256 + threadIdx.x;
  if (i < QKV_COLS) {
    const int s = i / 768, rem = i - s * 768;
    const int h = rem / 96, d = rem - h * 96;
    bq_out[i] = bq_in[h * 288 + d * 3 + s];
  }
  if (i < EMB) bp_out[i] = bp_in[i];
}

// ---------------- bt-GEMM: C[M,N] = A[M,K] @ Bt[N,K]^T + bias ----------------
// MODE 0: fp32 store to Cout [M,N], A row-major [M][Kd]
// MODE 1 (permuted qkv): tile_n < 1536 -> QK[row][1536] direct (coalesced);
//                        tile_n >= 1536 -> V: LDS transpose -> Vt[bh][d][n] coalesced
// MODE 2: like MODE 0 but A is head-major [b*8+h][2048][96]; k -> (h = k/96, d = k%96).
//         32-wide k-chunks never straddle heads (96 = 3*32), so h = k0/96 per chunk.
template<int MODE>
__global__ __launch_bounds__(256) void gemm_bt(
    const f16* __restrict__ A, const f16* __restrict__ Bt,
    const float* __restrict__ bias, float* __restrict__ Cout,
    f16* __restrict__ QK, f16* __restrict__ Vt,
    int M, int N, int Kd)
{
  __shared__ f16 smem[MODE == 1 ? 17408 : 8192];   // sA[4096]+sB[4096]; V-epilogue reuses as sT[128][136]
  f16* sA = smem;
  f16* sB = smem + 4096;
  const int tid  = threadIdx.x;
  const int wave = tid >> 6, lane = tid & 63;
  const int quad = lane >> 4, l16 = lane & 15;
  const int tile_m = blockIdx.y * 128, tile_n = blockIdx.x * 128;
  const int wm = (wave >> 1) * 64, wn = (wave & 1) * 64;

  f32x4 acc[4][4];
  for (int i = 0; i < 4; i++)
    for (int j = 0; j < 4; j++)
      acc[i][j] = f32x4{0.f, 0.f, 0.f, 0.f};

  for (int k0 = 0; k0 < Kd; k0 += 32) {
    __syncthreads();
#pragma unroll
    for (int it = 0; it < 2; it++) {
      const int ch  = (it * 4 + wave) * 64 + lane;   // 0..511
      const int row = ch >> 2, c8 = (ch & 3) * 8;
      if (MODE == 2) {
        const int grow = tile_m + row;
        const int bb = grow >> 11, n = grow & 2047;
        const int hh = k0 / 96, d0 = k0 - hh * 96 + c8;
        gl_lds16(A + ((size_t)(bb * NHEADS + hh) * SEQ + n) * HDIM + d0,
                 &sA[(it * 4 + wave) * 512]);
      } else {
        gl_lds16(A + (size_t)(tile_m + row) * Kd + k0 + c8, &sA[(it * 4 + wave) * 512]);
      }
      gl_lds16(Bt + (size_t)(tile_n + row) * Kd + k0 + c8, &sB[(it * 4 + wave) * 512]);
    }
    __syncthreads();

    f16x8 af[4], bfr[4];
    for (int i = 0; i < 4; i++) af[i]  = *(const f16x8*)&sA[(wm + i * 16 + l16) * 32 + quad * 8];
    for (int j = 0; j < 4; j++) bfr[j] = *(const f16x8*)&sB[(wn + j * 16 + l16) * 32 + quad * 8];
    for (int i = 0; i < 4; i++)
      for (int j = 0; j < 4; j++)
        acc[i][j] = __builtin_amdgcn_mfma_f32_16x16x32_f16(af[i], bfr[j], acc[i][j], 0, 0, 0);
  }

  // epilogue: C layout col=lane&15, row=quad*4+reg
  if (MODE == 1 && tile_n >= 1536) {
    // ---- V tile: LDS transpose then coalesced Vt writes ----
    __syncthreads();   // sA/sB dead, safe to overwrite
    f16* sT = smem;    // [128][136]
    for (int j = 0; j < 4; j++) {
      const int cl = wn + j * 16 + l16;
      const float bv = bias[tile_n + cl];
      for (int i = 0; i < 4; i++)
        for (int r = 0; r < 4; r++)
          sT[cl * 136 + wm + i * 16 + quad * 4 + r] = (f16)(acc[i][j][r] + bv);
    }
    __syncthreads();
    const int bb = tile_m >> 11;          // group-local batch
    const int n0 = tile_m & 2047;
#pragma unroll
    for (int l = 0; l < 8; l++) {
      const int cc = l * 256 + tid;       // 0..2047 chunks of 8 f16
      const int rh = cc >> 4, nof = (cc & 15) * 8;
      const int hd = (tile_n - 1536) + rh;
      const int h = hd / 96, d = hd - h * 96;
      f16x8 v = *(const f16x8*)&sT[rh * 136 + nof];
      *(f16x8*)(Vt + ((size_t)(bb * NHEADS + h) * HDIM + d) * SEQ + n0 + nof) = v;
    }
  } else {
    for (int j = 0; j < 4; j++) {
      const int col = tile_n + wn + j * 16 + l16;
      const float bv = bias[col];
      for (int i = 0; i < 4; i++) {
        for (int r = 0; r < 4; r++) {
          const int row = tile_m + wm + i * 16 + quad * 4 + r;
          const float fv = acc[i][j][r] + bv;
          if (MODE != 1) Cout[(size_t)row * N + col] = fv;
          else           QK  [(size_t)row * 1536 + col] = (f16)fv;  // Q cols 0..767, K 768..1535
        }
      }
    }
  }
}

// ---------------- flash attention ----------------
// r13 = r11 (session best, 158 us) + ONE provably-safe delta:
//   deferred l-sum: the per-kt 16-lane sum butterfly is deleted. l_run stays a
//   PER-LANE partial (alpha is row-uniform across the 16 lanes since m_run is
//   post-butterfly uniform), updated l = l*alpha + rsv_lane per kt; ONE butterfly
//   after the loop recovers the row sum (pure fp32 reorder, threshold 9.6e-3).
//   Deletes 32 of 64 dependent bpermutes per wave-kt (512/sweep -> 32 total).
// r12's (256,3) launch-bounds spill (VGPR 84, 245 MB scratch writes) REVERTED;
// r12's 3-block premise was void anyway: grid 512 = 2 blocks/CU is the cap.
// Everything else identical to r11: async staggered K/V staging via gl_lds with
// source-swizzled addresses, counted vmcnt(6), raw barriers, XCD swizzle,
// head-major Out, two 64-k sP halves.
//   sK[128][96]: 16B-unit rotation  phys = (u + row) % 12
//   sV[96][128]: 16B-unit XOR       phys = u ^ (d & 15)
//   sP[128][64]: 16B-unit XOR       phys = u ^ (row & 7)
__global__ __launch_bounds__(256, 2) void attn_k(
    const f16* __restrict__ QK, const f16* __restrict__ Vt,
    f16* __restrict__ Out /* [nb*8][2048][96] f16 */, int nbh)
{
  __shared__ f16 sK[128 * 96];
  __shared__ f16 sV[96 * 128];
  __shared__ f16 sP[128 * 64];
  const int tid  = threadIdx.x;
  const int wave = tid >> 6, lane = tid & 63;
  const int quad = lane >> 4, l16 = lane & 15;

  const int bid = blockIdx.x;
  const int xcd = bid & 7, idx = bid >> 3;   // dispatch round-robins XCDs on bid%8
  const int bh  = xcd * (nbh >> 3) + (idx >> 4);
  const int qt  = idx & 15;
  const int b = bh >> 3, h = bh & 7;

  const int wrow = wave * 32;                // this wave's q-row base (32 rows, ti=2)

  const f16* Qb = QK + (size_t)(b * SEQ + qt * 128 + wrow) * 1536 + h * 96;
  const f16* Kb = QK + (size_t)(b * SEQ) * 1536 + 768 + h * 96;
  const f16* Vb = Vt + (size_t)bh * HDIM * SEQ;

  // per-thread pre-swizzled staging source offsets (chunk ck = i*256 + tid):
  //  K: (krow,pu) -> src krow*1536 + ((pu - krow) mod 12)*8 ; dest linear ck*8
  //  V: (vd,pu)   -> src vd*SEQ + (pv ^ (vd&15))*8          ; dest linear ck*8
  int koff[6], voff[6];
#pragma unroll
  for (int i = 0; i < 6; i++) {
    const int ck = i * 256 + tid;
    const int krow = ck / 12, pu = ck - krow * 12;
    const int u = (pu + 12 - krow % 12) % 12;
    koff[i] = krow * 1536 + u * 8;
    const int vd = ck >> 4, pv = ck & 15;
    voff[i] = vd * SEQ + (pv ^ (vd & 15)) * 8;
  }

  f16x8 qf[2][3];
#pragma unroll
  for (int ti = 0; ti < 2; ti++)
#pragma unroll
    for (int kc = 0; kc < 3; kc++)
      qf[ti][kc] = *(const f16x8*)(Qb + (size_t)(ti * 16 + l16) * 1536 + kc * 32 + quad * 8);

  f32x4 oacc[2][6];
#pragma unroll
  for (int ti = 0; ti < 2; ti++)
#pragma unroll
    for (int dj = 0; dj < 6; dj++)
      oacc[ti][dj] = f32x4{0.f, 0.f, 0.f, 0.f};
  f32x4 m_run[2], l_run[2];
#pragma unroll
  for (int ti = 0; ti < 2; ti++) {
    m_run[ti] = f32x4{-1e30f, -1e30f, -1e30f, -1e30f};
    l_run[ti] = f32x4{0.f, 0.f, 0.f, 0.f};   // PER-LANE partial until final reduce
  }

  // prologue: issue K(0) then V(0) (order matters for vmcnt counting)
  {
#pragma unroll
    for (int i = 0; i < 6; i++) gl_lds16(Kb + koff[i], &sK[(i * 256 + wave * 64) * 8]);
#pragma unroll
    for (int i = 0; i < 6; i++) gl_lds16(Vb + voff[i], &sV[(i * 256 + wave * 64) * 8]);
  }

  const int NT = SEQ / 128;
  for (int kt = 0; kt < NT; kt++) {
    // #1: drain K(kt) (kt=0: drain everything incl. qf to make counts exact)
    if (kt == 0) asm volatile("s_waitcnt vmcnt(0)" ::: "memory");
    else         asm volatile("s_waitcnt vmcnt(6)" ::: "memory");
    __builtin_amdgcn_s_barrier();            // #2: sK(kt) visible to all waves
    __builtin_amdgcn_sched_barrier(0);

    // ---- QK^T: each kf read feeds both ti MFMAs ----
    f32x4 sacc[2][8];
#pragma unroll
    for (int ti = 0; ti < 2; ti++)
#pragma unroll
      for (int j = 0; j < 8; j++)
        sacc[ti][j] = f32x4{0.f, 0.f, 0.f, 0.f};
#pragma unroll
    for (int kc = 0; kc < 3; kc++) {
#pragma unroll
      for (int j = 0; j < 8; j++) {
        const int krow = j * 16 + l16;
        const f16x8 kf = *(const f16x8*)&sK[krow * 96 + ((kc * 4 + quad + krow) % 12) * 8];
        sacc[0][j] = __builtin_amdgcn_mfma_f32_16x16x32_f16(qf[0][kc], kf, sacc[0][j], 0, 0, 0);
        sacc[1][j] = __builtin_amdgcn_mfma_f32_16x16x32_f16(qf[1][kc], kf, sacc[1][j], 0, 0, 0);
      }
    }

    __builtin_amdgcn_sched_barrier(0);
    __builtin_amdgcn_s_barrier();            // #3: all waves done reading sK
    if (kt < NT - 1) {                       // issue K(kt+1) -> flies during softmax+PV
      const f16* kb = Kb + (size_t)((kt + 1) * 128) * 1536;
#pragma unroll
      for (int i = 0; i < 6; i++) gl_lds16(kb + koff[i], &sK[(i * 256 + wave * 64) * 8]);
    }
    __builtin_amdgcn_sched_barrier(0);

    // ---- stats per ti: max, alpha, rescale ----
    f32x4 rsv[2];
#pragma unroll
    for (int ti = 0; ti < 2; ti++) {
      f32x4 vmx = sacc[ti][0];
#pragma unroll
      for (int j = 1; j < 8; j++) vmx = vmax4(vmx, sacc[ti][j]);
      for (int m = 1; m < 16; m <<= 1) vmx = vmax4(vmx, shflx4(vmx, m));
      const f32x4 nm = vmax4(m_run[ti], vmx);
      f32x4 alpha;
      alpha[0] = __expf(m_run[ti][0] - nm[0]); alpha[1] = __expf(m_run[ti][1] - nm[1]);
      alpha[2] = __expf(m_run[ti][2] - nm[2]); alpha[3] = __expf(m_run[ti][3] - nm[3]);
      m_run[ti] = nm;
      l_run[ti] *= alpha;                    // per-lane partial, alpha row-uniform
      rsv[ti] = f32x4{0.f, 0.f, 0.f, 0.f};
#pragma unroll
      for (int dj = 0; dj < 6; dj++) oacc[ti][dj] *= alpha;
    }

    // #4: drain V(kt) (last iter: nothing newer outstanding -> 0)
    if (kt < NT - 1) asm volatile("s_waitcnt vmcnt(6)" ::: "memory");
    else             asm volatile("s_waitcnt vmcnt(0)" ::: "memory");
    __builtin_amdgcn_s_barrier();            // #5: sV(kt) visible to all waves
    __builtin_amdgcn_sched_barrier(0);

    // ---- two 64-k halves: write P (XOR-swizzled sP) -> PV (vf read feeds both ti) ----
#pragma unroll
    for (int c2 = 0; c2 < 2; c2++) {
#pragma unroll
      for (int ti = 0; ti < 2; ti++) {
        const int prow = wrow + ti * 16 + quad * 4;
#pragma unroll
        for (int jl = 0; jl < 4; jl++) {
          const int j = c2 * 4 + jl;
          f32x4 p;
          p[0] = __expf(sacc[ti][j][0] - m_run[ti][0]);
          p[1] = __expf(sacc[ti][j][1] - m_run[ti][1]);
          p[2] = __expf(sacc[ti][j][2] - m_run[ti][2]);
          p[3] = __expf(sacc[ti][j][3] - m_run[ti][3]);
          rsv[ti] += p;
          const int unit = jl * 2 + (l16 >> 3);   // 16B unit of col = jl*16+l16
          const int within = l16 & 7;
#pragma unroll
          for (int rr = 0; rr < 4; rr++) {
            const int row = prow + rr;
            sP[row * 64 + (unit ^ (row & 7)) * 8 + within] = (f16)p[rr];
          }
        }
      }
#pragma unroll
      for (int kc2 = 0; kc2 < 2; kc2++) {
        const f16x8 pf0 = *(const f16x8*)&sP[(wrow + l16) * 64
                                            + ((kc2 * 4 + quad) ^ (l16 & 7)) * 8];
        const f16x8 pf1 = *(const f16x8*)&sP[(wrow + 16 + l16) * 64
                                            + ((kc2 * 4 + quad) ^ (l16 & 7)) * 8];
#pragma unroll
        for (int dj = 0; dj < 6; dj++) {
          const int vph = (c2 * 8 + kc2 * 4 + quad) ^ l16;   // d&15 == l16
          const f16x8 vf = *(const f16x8*)&sV[(dj * 16 + l16) * 128 + vph * 8];
          oacc[0][dj] = __builtin_amdgcn_mfma_f32_16x16x32_f16(pf0, vf, oacc[0][dj], 0, 0, 0);
          oacc[1][dj] = __builtin_amdgcn_mfma_f32_16x16x32_f16(pf1, vf, oacc[1][dj], 0, 0, 0);
        }
      }
    }

    __builtin_amdgcn_sched_barrier(0);
    __builtin_amdgcn_s_barrier();            // #6: all waves done reading sV
    if (kt < NT - 1) {                       // issue V(kt+1) -> flies through next QK^T
      const f16* vb = Vb + (kt + 1) * 128;
#pragma unroll
      for (int i = 0; i < 6; i++) gl_lds16(vb + voff[i], &sV[(i * 256 + wave * 64) * 8]);
    }
    __builtin_amdgcn_sched_barrier(0);

    // ---- accumulate per-lane partial sums (NO butterfly here) ----
#pragma unroll
    for (int ti = 0; ti < 2; ti++) l_run[ti] += rsv[ti];
  }

  // ---- single deferred row-sum reduction (32 bpermutes total, was 512) ----
#pragma unroll
  for (int ti = 0; ti < 2; ti++)
    for (int m = 1; m < 16; m <<= 1) l_run[ti] += shflx4(l_run[ti], m);

  const float inv_scale = 0.10206207261596577f;  // 1/sqrt(96), applied AFTER softmax per ref
#pragma unroll
  for (int ti = 0; ti < 2; ti++) {
#pragma unroll
    for (int r = 0; r < 4; r++) {
      const int qrow = qt * 128 + wrow + ti * 16 + quad * 4 + r;
      const float invl = inv_scale / l_run[ti][r];
      const size_t base = ((size_t)bh * SEQ + qrow) * HDIM;   // head-major out
#pragma unroll
      for (int dj = 0; dj < 6; dj++)
        Out[base + dj * 16 + l16] = (f16)(oacc[ti][dj][r] * invl);
    }
  }
}

// ---------------- launch ----------------
extern "C" void kernel_launch(void* const* d_in, const int* in_sizes, int n_in,
                              void* d_out, int out_size, void* d_ws, size_t ws_size,
                              hipStream_t stream) {
  const float* x      = (const float*)d_in[0];
  const float* w_qkv  = (const float*)d_in[1];
  const float* b_qkv  = (const float*)d_in[2];
  const float* w_proj = (const float*)d_in[3];
  const float* b_proj = (const float*)d_in[4];
  float* outF = (float*)d_out;   // fp32 output

  const size_t fixed = 256 + (size_t)QKV_COLS * EMB * 2 + (size_t)EMB * EMB * 2
                     + QKV_COLS * 4 + EMB * 4 + 256;
  const size_t perb = (size_t)4 * PB * 2;  // QK(2) + Vt(1) + attn(1) per batch, in PB units
  int nb = (ws_size >= fixed + 4 * perb) ? 4 : (ws_size >= fixed + 2 * perb) ? 2 : 1;

  char* ws = (char*)d_ws;
  ws += 256;
  f16*   wqkvT  = (f16*)ws;   ws += (size_t)QKV_COLS * EMB * 2;
  f16*   wprojT = (f16*)ws;   ws += (size_t)EMB * EMB * 2;
  float* bq     = (float*)ws; ws += (size_t)QKV_COLS * 4;
  float* bp     = (float*)ws; ws += (size_t)EMB * 4 + 256;
  f16* QK   = (f16*)ws;       ws += (size_t)nb * 2 * PB * 2;   // [nb*2048][1536]
  f16* Vt   = (f16*)ws;       ws += (size_t)nb * PB * 2;       // [nb*8][96][2048]
  f16* attn = (f16*)ws;       ws += (size_t)nb * PB * 2;       // [nb*8][2048][96] head-major

  wqkv_perm_k<<<(QKV_COLS * (EMB / 8) + 255) / 256, 256, 0, stream>>>(w_qkv, wqkvT);
  wproj_t_k<<<(EMB * (EMB / 8) + 255) / 256, 256, 0, stream>>>(w_proj, wprojT);
  bias_perm_k<<<(QKV_COLS + 255) / 256, 256, 0, stream>>>(b_qkv, bq, b_proj, bp);

  for (int outer = 0; outer < BATCH / nb; outer++) {
    const int bbase = outer * nb;
    const size_t goff = (size_t)bbase * PB;
    f16* xg = (f16*)(outF + goff);           // stage f16 x inside fp32 out region (dead before proj)
    const int n8 = (int)((size_t)nb * PB / 8);
    conv_x8_k<<<(n8 + 255) / 256, 256, 0, stream>>>(x, goff, xg, n8);

    dim3 g1(QKV_COLS / 128, nb * SEQ / 128);
    gemm_bt<1><<<g1, 256, 0, stream>>>(xg, wqkvT, bq, nullptr, QK, Vt,
                                       nb * SEQ, QKV_COLS, EMB);

    attn_k<<<dim3(16 * nb * NHEADS), 256, 0, stream>>>(QK, Vt, attn, nb * NHEADS);

    dim3 g3(EMB / 128, nb * SEQ / 128);
    gemm_bt<2><<<g3, 256, 0, stream>>>(attn, wprojT, bp, outF + goff,
                                       nullptr, nullptr,
                                       nb * SEQ, EMB, EMB);
  }
}

// Round 14
// 305.428 us; speedup vs baseline: 1.7830x; 1.0789x over previous
//
#include <hip/hip_runtime.h>
#include <hip/hip_bf16.h>

#define EMB 768
#define NHEADS 8
#define HDIM 96
#define SEQ 2048
#define BATCH 4
#define QKV_COLS 2304
#define PB ((size_t)SEQ * EMB)   // per-batch elements

typedef _Float16 f16;
typedef _Float16 f16x8 __attribute__((ext_vector_type(8)));
typedef float f32x4 __attribute__((ext_vector_type(4)));

__device__ __forceinline__ void gl_lds16(const f16* g, f16* l) {
  __builtin_amdgcn_global_load_lds((const __attribute__((address_space(1))) void*)g,
                                   (__attribute__((address_space(3))) void*)l, 16, 0, 0);
}
__device__ __forceinline__ f32x4 shflx4(f32x4 v, int m) {
  f32x4 r;
  r[0] = __shfl_xor(v[0], m); r[1] = __shfl_xor(v[1], m);
  r[2] = __shfl_xor(v[2], m); r[3] = __shfl_xor(v[3], m);
  return r;
}
__device__ __forceinline__ f32x4 vmax4(f32x4 a, f32x4 b) {
  f32x4 r;
  r[0] = fmaxf(a[0], b[0]); r[1] = fmaxf(a[1], b[1]);
  r[2] = fmaxf(a[2], b[2]); r[3] = fmaxf(a[3], b[3]);
  return r;
}

// ---------------- conversions ----------------
__global__ __launch_bounds__(256) void conv_x8_k(const float* __restrict__ in, size_t in_off,
                                                 f16* __restrict__ out, int n8) {
  int i = blockIdx.x * 256 + threadIdx.x;
  if (i >= n8) return;
  const float4 a = *(const float4*)(in + in_off + (size_t)i * 8);
  const float4 b = *(const float4*)(in + in_off + (size_t)i * 8 + 4);
  f16x8 o;
  o[0] = (f16)a.x; o[1] = (f16)a.y; o[2] = (f16)a.z; o[3] = (f16)a.w;
  o[4] = (f16)b.x; o[5] = (f16)b.y; o[6] = (f16)b.z; o[7] = (f16)b.w;
  *(f16x8*)(out + (size_t)i * 8) = o;
}

// qkv weight: transpose + column-permute. out[col'][r], col' = s*768+h*96+d,
// original col c = h*288+d*3+s. Output-indexed -> coalesced 16B writes.
__global__ __launch_bounds__(256) void wqkv_perm_k(const float* __restrict__ in,
                                                   f16* __restrict__ out) {
  int t = blockIdx.x * 256 + threadIdx.x;          // 0 .. 2304*96-1
  if (t >= QKV_COLS * (EMB / 8)) return;
  const int colp = t / (EMB / 8);
  const int r8 = (t - colp * (EMB / 8)) * 8;
  const int s = colp / 768, rem = colp - s * 768;
  const int h = rem / 96, d = rem - h * 96;
  const int c = h * 288 + d * 3 + s;
  f16x8 o;
#pragma unroll
  for (int i = 0; i < 8; i++) o[i] = (f16)in[(size_t)(r8 + i) * QKV_COLS + c];
  *(f16x8*)(out + (size_t)colp * EMB + r8) = o;
}

// proj weight: plain transpose, output-indexed.
__global__ __launch_bounds__(256) void wproj_t_k(const float* __restrict__ in,
                                                 f16* __restrict__ out) {
  int t = blockIdx.x * 256 + threadIdx.x;          // 0 .. 768*96-1
  if (t >= EMB * (EMB / 8)) return;
  const int cp = t / (EMB / 8);
  const int r8 = (t - cp * (EMB / 8)) * 8;
  f16x8 o;
#pragma unroll
  for (int i = 0; i < 8; i++) o[i] = (f16)in[(size_t)(r8 + i) * EMB + cp];
  *(f16x8*)(out + (size_t)cp * EMB + r8) = o;
}

// bias: permute qkv bias to col' space; copy proj bias.
__global__ __launch_bounds__(256) void bias_perm_k(const float* __restrict__ bq_in,
                                                   float* __restrict__ bq_out,
                                                   const float* __restrict__ bp_in,
                                                   float* __restrict__ bp_out) {
  int i = blockIdx.x * 256 + threadIdx.x;
  if (i < QKV_COLS) {
    const int s = i / 768, rem = i - s * 768;
    const int h = rem / 96, d = rem - h * 96;
    bq_out[i] = bq_in[h * 288 + d * 3 + s];
  }
  if (i < EMB) bp_out[i] = bp_in[i];
}

// ---------------- bt-GEMM: C[M,N] = A[M,K] @ Bt[N,K]^T + bias ----------------
// MODE 0: fp32 store to Cout [M,N], A row-major [M][Kd]
// MODE 1 (permuted qkv): tile_n < 1536 -> QK[row][1536] direct (coalesced);
//                        tile_n >= 1536 -> V: LDS transpose -> Vt[bh][d][n] coalesced
// MODE 2: like MODE 0 but A is head-major [b*8+h][2048][96]; k -> (h = k/96, d = k%96).
//         32-wide k-chunks never straddle heads (96 = 3*32), so h = k0/96 per chunk.
template<int MODE>
__global__ __launch_bounds__(256) void gemm_bt(
    const f16* __restrict__ A, const f16* __restrict__ Bt,
    const float* __restrict__ bias, float* __restrict__ Cout,
    f16* __restrict__ QK, f16* __restrict__ Vt,
    int M, int N, int Kd)
{
  __shared__ f16 smem[MODE == 1 ? 17408 : 8192];   // sA[4096]+sB[4096]; V-epilogue reuses as sT[128][136]
  f16* sA = smem;
  f16* sB = smem + 4096;
  const int tid  = threadIdx.x;
  const int wave = tid >> 6, lane = tid & 63;
  const int quad = lane >> 4, l16 = lane & 15;
  const int tile_m = blockIdx.y * 128, tile_n = blockIdx.x * 128;
  const int wm = (wave >> 1) * 64, wn = (wave & 1) * 64;

  f32x4 acc[4][4];
  for (int i = 0; i < 4; i++)
    for (int j = 0; j < 4; j++)
      acc[i][j] = f32x4{0.f, 0.f, 0.f, 0.f};

  for (int k0 = 0; k0 < Kd; k0 += 32) {
    __syncthreads();
#pragma unroll
    for (int it = 0; it < 2; it++) {
      const int ch  = (it * 4 + wave) * 64 + lane;   // 0..511
      const int row = ch >> 2, c8 = (ch & 3) * 8;
      if (MODE == 2) {
        const int grow = tile_m + row;
        const int bb = grow >> 11, n = grow & 2047;
        const int hh = k0 / 96, d0 = k0 - hh * 96 + c8;
        gl_lds16(A + ((size_t)(bb * NHEADS + hh) * SEQ + n) * HDIM + d0,
                 &sA[(it * 4 + wave) * 512]);
      } else {
        gl_lds16(A + (size_t)(tile_m + row) * Kd + k0 + c8, &sA[(it * 4 + wave) * 512]);
      }
      gl_lds16(Bt + (size_t)(tile_n + row) * Kd + k0 + c8, &sB[(it * 4 + wave) * 512]);
    }
    __syncthreads();

    f16x8 af[4], bfr[4];
    for (int i = 0; i < 4; i++) af[i]  = *(const f16x8*)&sA[(wm + i * 16 + l16) * 32 + quad * 8];
    for (int j = 0; j < 4; j++) bfr[j] = *(const f16x8*)&sB[(wn + j * 16 + l16) * 32 + quad * 8];
    for (int i = 0; i < 4; i++)
      for (int j = 0; j < 4; j++)
        acc[i][j] = __builtin_amdgcn_mfma_f32_16x16x32_f16(af[i], bfr[j], acc[i][j], 0, 0, 0);
  }

  // epilogue: C layout col=lane&15, row=quad*4+reg
  if (MODE == 1 && tile_n >= 1536) {
    // ---- V tile: LDS transpose then coalesced Vt writes ----
    __syncthreads();   // sA/sB dead, safe to overwrite
    f16* sT = smem;    // [128][136]
    for (int j = 0; j < 4; j++) {
      const int cl = wn + j * 16 + l16;
      const float bv = bias[tile_n + cl];
      for (int i = 0; i < 4; i++)
        for (int r = 0; r < 4; r++)
          sT[cl * 136 + wm + i * 16 + quad * 4 + r] = (f16)(acc[i][j][r] + bv);
    }
    __syncthreads();
    const int bb = tile_m >> 11;          // group-local batch
    const int n0 = tile_m & 2047;
#pragma unroll
    for (int l = 0; l < 8; l++) {
      const int cc = l * 256 + tid;       // 0..2047 chunks of 8 f16
      const int rh = cc >> 4, nof = (cc & 15) * 8;
      const int hd = (tile_n - 1536) + rh;
      const int h = hd / 96, d = hd - h * 96;
      f16x8 v = *(const f16x8*)&sT[rh * 136 + nof];
      *(f16x8*)(Vt + ((size_t)(bb * NHEADS + h) * HDIM + d) * SEQ + n0 + nof) = v;
    }
  } else {
    for (int j = 0; j < 4; j++) {
      const int col = tile_n + wn + j * 16 + l16;
      const float bv = bias[col];
      for (int i = 0; i < 4; i++) {
        for (int r = 0; r < 4; r++) {
          const int row = tile_m + wm + i * 16 + quad * 4 + r;
          const float fv = acc[i][j][r] + bv;
          if (MODE != 1) Cout[(size_t)row * N + col] = fv;
          else           QK  [(size_t)row * 1536 + col] = (f16)fv;  // Q cols 0..767, K 768..1535
        }
      }
    }
  }
}

// ---------------- flash attention ----------------
// r14 = r13 (143 us) + defer-max (T13, RESCALE_THRESHOLD=8):
//   per kt compute only the PER-LANE max (no butterfly). If
//   __all(vmx <= m_run + 8) -- wave-uniform ballot, uniform branch -- skip the
//   butterfly + alpha + l/oacc rescale entirely. P = exp(s - m_old) <= e^8 =
//   2981 < 65504 (f16 max); softmax's reference constant cancels in out = PV/l,
//   only per-row uniformity matters and m_old is already row-uniform. kt=0
//   (m=-1e30) always triggers the full path -> correct init. Scores have
//   sigma~10 so after the first tiles the skip rate is ~90%+: deletes the
//   serial 32-bpermute chain + ~60 VALU rescale ops from most iterations.
// Everything else identical to r13: deferred l-sum (one butterfly after loop),
// async staggered K/V staging (gl_lds, source-swizzled, counted vmcnt(6), raw
// barriers), XCD swizzle, head-major Out, two 64-k sP halves.
//   sK[128][96]: 16B-unit rotation  phys = (u + row) % 12
//   sV[96][128]: 16B-unit XOR       phys = u ^ (d & 15)
//   sP[128][64]: 16B-unit XOR       phys = u ^ (row & 7)
__global__ __launch_bounds__(256, 2) void attn_k(
    const f16* __restrict__ QK, const f16* __restrict__ Vt,
    f16* __restrict__ Out /* [nb*8][2048][96] f16 */, int nbh)
{
  __shared__ f16 sK[128 * 96];
  __shared__ f16 sV[96 * 128];
  __shared__ f16 sP[128 * 64];
  const int tid  = threadIdx.x;
  const int wave = tid >> 6, lane = tid & 63;
  const int quad = lane >> 4, l16 = lane & 15;

  const int bid = blockIdx.x;
  const int xcd = bid & 7, idx = bid >> 3;   // dispatch round-robins XCDs on bid%8
  const int bh  = xcd * (nbh >> 3) + (idx >> 4);
  const int qt  = idx & 15;
  const int b = bh >> 3, h = bh & 7;

  const int wrow = wave * 32;                // this wave's q-row base (32 rows, ti=2)

  const f16* Qb = QK + (size_t)(b * SEQ + qt * 128 + wrow) * 1536 + h * 96;
  const f16* Kb = QK + (size_t)(b * SEQ) * 1536 + 768 + h * 96;
  const f16* Vb = Vt + (size_t)bh * HDIM * SEQ;

  // per-thread pre-swizzled staging source offsets (chunk ck = i*256 + tid):
  //  K: (krow,pu) -> src krow*1536 + ((pu - krow) mod 12)*8 ; dest linear ck*8
  //  V: (vd,pu)   -> src vd*SEQ + (pv ^ (vd&15))*8          ; dest linear ck*8
  int koff[6], voff[6];
#pragma unroll
  for (int i = 0; i < 6; i++) {
    const int ck = i * 256 + tid;
    const int krow = ck / 12, pu = ck - krow * 12;
    const int u = (pu + 12 - krow % 12) % 12;
    koff[i] = krow * 1536 + u * 8;
    const int vd = ck >> 4, pv = ck & 15;
    voff[i] = vd * SEQ + (pv ^ (vd & 15)) * 8;
  }

  f16x8 qf[2][3];
#pragma unroll
  for (int ti = 0; ti < 2; ti++)
#pragma unroll
    for (int kc = 0; kc < 3; kc++)
      qf[ti][kc] = *(const f16x8*)(Qb + (size_t)(ti * 16 + l16) * 1536 + kc * 32 + quad * 8);

  f32x4 oacc[2][6];
#pragma unroll
  for (int ti = 0; ti < 2; ti++)
#pragma unroll
    for (int dj = 0; dj < 6; dj++)
      oacc[ti][dj] = f32x4{0.f, 0.f, 0.f, 0.f};
  f32x4 m_run[2], l_run[2];
#pragma unroll
  for (int ti = 0; ti < 2; ti++) {
    m_run[ti] = f32x4{-1e30f, -1e30f, -1e30f, -1e30f};
    l_run[ti] = f32x4{0.f, 0.f, 0.f, 0.f};   // PER-LANE partial until final reduce
  }

  // prologue: issue K(0) then V(0) (order matters for vmcnt counting)
  {
#pragma unroll
    for (int i = 0; i < 6; i++) gl_lds16(Kb + koff[i], &sK[(i * 256 + wave * 64) * 8]);
#pragma unroll
    for (int i = 0; i < 6; i++) gl_lds16(Vb + voff[i], &sV[(i * 256 + wave * 64) * 8]);
  }

  const int NT = SEQ / 128;
  for (int kt = 0; kt < NT; kt++) {
    // #1: drain K(kt) (kt=0: drain everything incl. qf to make counts exact)
    if (kt == 0) asm volatile("s_waitcnt vmcnt(0)" ::: "memory");
    else         asm volatile("s_waitcnt vmcnt(6)" ::: "memory");
    __builtin_amdgcn_s_barrier();            // #2: sK(kt) visible to all waves
    __builtin_amdgcn_sched_barrier(0);

    // ---- QK^T: each kf read feeds both ti MFMAs ----
    f32x4 sacc[2][8];
#pragma unroll
    for (int ti = 0; ti < 2; ti++)
#pragma unroll
      for (int j = 0; j < 8; j++)
        sacc[ti][j] = f32x4{0.f, 0.f, 0.f, 0.f};
#pragma unroll
    for (int kc = 0; kc < 3; kc++) {
#pragma unroll
      for (int j = 0; j < 8; j++) {
        const int krow = j * 16 + l16;
        const f16x8 kf = *(const f16x8*)&sK[krow * 96 + ((kc * 4 + quad + krow) % 12) * 8];
        sacc[0][j] = __builtin_amdgcn_mfma_f32_16x16x32_f16(qf[0][kc], kf, sacc[0][j], 0, 0, 0);
        sacc[1][j] = __builtin_amdgcn_mfma_f32_16x16x32_f16(qf[1][kc], kf, sacc[1][j], 0, 0, 0);
      }
    }

    __builtin_amdgcn_sched_barrier(0);
    __builtin_amdgcn_s_barrier();            // #3: all waves done reading sK
    if (kt < NT - 1) {                       // issue K(kt+1) -> flies during softmax+PV
      const f16* kb = Kb + (size_t)((kt + 1) * 128) * 1536;
#pragma unroll
      for (int i = 0; i < 6; i++) gl_lds16(kb + koff[i], &sK[(i * 256 + wave * 64) * 8]);
    }
    __builtin_amdgcn_sched_barrier(0);

    // ---- stats per ti: defer-max (skip butterfly+rescale when max didn't grow) ----
    f32x4 rsv[2];
#pragma unroll
    for (int ti = 0; ti < 2; ti++) {
      f32x4 vmx = sacc[ti][0];
#pragma unroll
      for (int j = 1; j < 8; j++) vmx = vmax4(vmx, sacc[ti][j]);
      const int ok = __all(vmx[0] <= m_run[ti][0] + 8.f &&
                           vmx[1] <= m_run[ti][1] + 8.f &&
                           vmx[2] <= m_run[ti][2] + 8.f &&
                           vmx[3] <= m_run[ti][3] + 8.f);
      if (!ok) {
        for (int m = 1; m < 16; m <<= 1) vmx = vmax4(vmx, shflx4(vmx, m));
        const f32x4 nm = vmax4(m_run[ti], vmx);
        f32x4 alpha;
        alpha[0] = __expf(m_run[ti][0] - nm[0]); alpha[1] = __expf(m_run[ti][1] - nm[1]);
        alpha[2] = __expf(m_run[ti][2] - nm[2]); alpha[3] = __expf(m_run[ti][3] - nm[3]);
        m_run[ti] = nm;
        l_run[ti] *= alpha;                  // per-lane partial, alpha row-uniform
#pragma unroll
        for (int dj = 0; dj < 6; dj++) oacc[ti][dj] *= alpha;
      }
      rsv[ti] = f32x4{0.f, 0.f, 0.f, 0.f};
    }

    // #4: drain V(kt) (last iter: nothing newer outstanding -> 0)
    if (kt < NT - 1) asm volatile("s_waitcnt vmcnt(6)" ::: "memory");
    else             asm volatile("s_waitcnt vmcnt(0)" ::: "memory");
    __builtin_amdgcn_s_barrier();            // #5: sV(kt) visible to all waves
    __builtin_amdgcn_sched_barrier(0);

    // ---- two 64-k halves: write P (XOR-swizzled sP) -> PV (vf read feeds both ti) ----
#pragma unroll
    for (int c2 = 0; c2 < 2; c2++) {
#pragma unroll
      for (int ti = 0; ti < 2; ti++) {
        const int prow = wrow + ti * 16 + quad * 4;
#pragma unroll
        for (int jl = 0; jl < 4; jl++) {
          const int j = c2 * 4 + jl;
          f32x4 p;
          p[0] = __expf(sacc[ti][j][0] - m_run[ti][0]);
          p[1] = __expf(sacc[ti][j][1] - m_run[ti][1]);
          p[2] = __expf(sacc[ti][j][2] - m_run[ti][2]);
          p[3] = __expf(sacc[ti][j][3] - m_run[ti][3]);
          rsv[ti] += p;
          const int unit = jl * 2 + (l16 >> 3);   // 16B unit of col = jl*16+l16
          const int within = l16 & 7;
#pragma unroll
          for (int rr = 0; rr < 4; rr++) {
            const int row = prow + rr;
            sP[row * 64 + (unit ^ (row & 7)) * 8 + within] = (f16)p[rr];
          }
        }
      }
#pragma unroll
      for (int kc2 = 0; kc2 < 2; kc2++) {
        const f16x8 pf0 = *(const f16x8*)&sP[(wrow + l16) * 64
                                            + ((kc2 * 4 + quad) ^ (l16 & 7)) * 8];
        const f16x8 pf1 = *(const f16x8*)&sP[(wrow + 16 + l16) * 64
                                            + ((kc2 * 4 + quad) ^ (l16 & 7)) * 8];
#pragma unroll
        for (int dj = 0; dj < 6; dj++) {
          const int vph = (c2 * 8 + kc2 * 4 + quad) ^ l16;   // d&15 == l16
          const f16x8 vf = *(const f16x8*)&sV[(dj * 16 + l16) * 128 + vph * 8];
          oacc[0][dj] = __builtin_amdgcn_mfma_f32_16x16x32_f16(pf0, vf, oacc[0][dj], 0, 0, 0);
          oacc[1][dj] = __builtin_amdgcn_mfma_f32_16x16x32_f16(pf1, vf, oacc[1][dj], 0, 0, 0);
        }
      }
    }

    __builtin_amdgcn_sched_barrier(0);
    __builtin_amdgcn_s_barrier();            // #6: all waves done reading sV
    if (kt < NT - 1) {                       // issue V(kt+1) -> flies through next QK^T
      const f16* vb = Vb + (kt + 1) * 128;
#pragma unroll
      for (int i = 0; i < 6; i++) gl_lds16(vb + voff[i], &sV[(i * 256 + wave * 64) * 8]);
    }
    __builtin_amdgcn_sched_barrier(0);

    // ---- accumulate per-lane partial sums (NO butterfly here) ----
#pragma unroll
    for (int ti = 0; ti < 2; ti++) l_run[ti] += rsv[ti];
  }

  // ---- single deferred row-sum reduction (32 bpermutes total) ----
#pragma unroll
  for (int ti = 0; ti < 2; ti++)
    for (int m = 1; m < 16; m <<= 1) l_run[ti] += shflx4(l_run[ti], m);

  const float inv_scale = 0.10206207261596577f;  // 1/sqrt(96), applied AFTER softmax per ref
#pragma unroll
  for (int ti = 0; ti < 2; ti++) {
#pragma unroll
    for (int r = 0; r < 4; r++) {
      const int qrow = qt * 128 + wrow + ti * 16 + quad * 4 + r;
      const float invl = inv_scale / l_run[ti][r];
      const size_t base = ((size_t)bh * SEQ + qrow) * HDIM;   // head-major out
#pragma unroll
      for (int dj = 0; dj < 6; dj++)
        Out[base + dj * 16 + l16] = (f16)(oacc[ti][dj][r] * invl);
    }
  }
}

// ---------------- launch ----------------
extern "C" void kernel_launch(void* const* d_in, const int* in_sizes, int n_in,
                              void* d_out, int out_size, void* d_ws, size_t ws_size,
                              hipStream_t stream) {
  const float* x      = (const float*)d_in[0];
  const float* w_qkv  = (const float*)d_in[1];
  const float* b_qkv  = (const float*)d_in[2];
  const float* w_proj = (const float*)d_in[3];
  const float* b_proj = (const float*)d_in[4];
  float* outF = (float*)d_out;   // fp32 output

  const size_t fixed = 256 + (size_t)QKV_COLS * EMB * 2 + (size_t)EMB * EMB * 2
                     + QKV_COLS * 4 + EMB * 4 + 256;
  const size_t perb = (size_t)4 * PB * 2;  // QK(2) + Vt(1) + attn(1) per batch, in PB units
  int nb = (ws_size >= fixed + 4 * perb) ? 4 : (ws_size >= fixed + 2 * perb) ? 2 : 1;

  char* ws = (char*)d_ws;
  ws += 256;
  f16*   wqkvT  = (f16*)ws;   ws += (size_t)QKV_COLS * EMB * 2;
  f16*   wprojT = (f16*)ws;   ws += (size_t)EMB * EMB * 2;
  float* bq     = (float*)ws; ws += (size_t)QKV_COLS * 4;
  float* bp     = (float*)ws; ws += (size_t)EMB * 4 + 256;
  f16* QK   = (f16*)ws;       ws += (size_t)nb * 2 * PB * 2;   // [nb*2048][1536]
  f16* Vt   = (f16*)ws;       ws += (size_t)nb * PB * 2;       // [nb*8][96][2048]
  f16* attn = (f16*)ws;       ws += (size_t)nb * PB * 2;       // [nb*8][2048][96] head-major

  wqkv_perm_k<<<(QKV_COLS * (EMB / 8) + 255) / 256, 256, 0, stream>>>(w_qkv, wqkvT);
  wproj_t_k<<<(EMB * (EMB / 8) + 255) / 256, 256, 0, stream>>>(w_proj, wprojT);
  bias_perm_k<<<(QKV_COLS + 255) / 256, 256, 0, stream>>>(b_qkv, bq, b_proj, bp);

  for (int outer = 0; outer < BATCH / nb; outer++) {
    const int bbase = outer * nb;
    const size_t goff = (size_t)bbase * PB;
    f16* xg = (f16*)(outF + goff);           // stage f16 x inside fp32 out region (dead before proj)
    const int n8 = (int)((size_t)nb * PB / 8);
    conv_x8_k<<<(n8 + 255) / 256, 256, 0, stream>>>(x, goff, xg, n8);

    dim3 g1(QKV_COLS / 128, nb * SEQ / 128);
    gemm_bt<1><<<g1, 256, 0, stream>>>(xg, wqkvT, bq, nullptr, QK, Vt,
                                       nb * SEQ, QKV_COLS, EMB);

    attn_k<<<dim3(16 * nb * NHEADS), 256, 0, stream>>>(QK, Vt, attn, nb * NHEADS);

    dim3 g3(EMB / 128, nb * SEQ / 128);
    gemm_bt<2><<<g3, 256, 0, stream>>>(attn, wprojT, bp, outF + goff,
                                       nullptr, nullptr,
                                       nb * SEQ, EMB, EMB);
  }
}

// Round 15
// 290.367 us; speedup vs baseline: 1.8754x; 1.0519x over previous
//
#include <hip/hip_runtime.h>
#include <hip/hip_bf16.h>

#define EMB 768
#define NHEADS 8
#define HDIM 96
#define SEQ 2048
#define BATCH 4
#define QKV_COLS 2304
#define PB ((size_t)SEQ * EMB)   // per-batch elements

typedef _Float16 f16;
typedef _Float16 f16x8 __attribute__((ext_vector_type(8)));
typedef float f32x4 __attribute__((ext_vector_type(4)));

__device__ __forceinline__ void gl_lds16(const f16* g, f16* l) {
  __builtin_amdgcn_global_load_lds((const __attribute__((address_space(1))) void*)g,
                                   (__attribute__((address_space(3))) void*)l, 16, 0, 0);
}
__device__ __forceinline__ f32x4 shflx4(f32x4 v, int m) {
  f32x4 r;
  r[0] = __shfl_xor(v[0], m); r[1] = __shfl_xor(v[1], m);
  r[2] = __shfl_xor(v[2], m); r[3] = __shfl_xor(v[3], m);
  return r;
}
__device__ __forceinline__ f32x4 vmax4(f32x4 a, f32x4 b) {
  f32x4 r;
  r[0] = fmaxf(a[0], b[0]); r[1] = fmaxf(a[1], b[1]);
  r[2] = fmaxf(a[2], b[2]); r[3] = fmaxf(a[3], b[3]);
  return r;
}

// ---------------- conversions ----------------
__global__ __launch_bounds__(256) void conv_x8_k(const float* __restrict__ in, size_t in_off,
                                                 f16* __restrict__ out, int n8) {
  int i = blockIdx.x * 256 + threadIdx.x;
  if (i >= n8) return;
  const float4 a = *(const float4*)(in + in_off + (size_t)i * 8);
  const float4 b = *(const float4*)(in + in_off + (size_t)i * 8 + 4);
  f16x8 o;
  o[0] = (f16)a.x; o[1] = (f16)a.y; o[2] = (f16)a.z; o[3] = (f16)a.w;
  o[4] = (f16)b.x; o[5] = (f16)b.y; o[6] = (f16)b.z; o[7] = (f16)b.w;
  *(f16x8*)(out + (size_t)i * 8) = o;
}

// ---------------- merged weight preprocessing (r15) ----------------
// Replaces wqkv_perm_k + wproj_t_k + bias_perm_k (3 launches, scalar strided
// reads at 16x line-overfetch) with ONE kernel doing coalesced 32x32 LDS-tile
// transposes. out[perm(c)][r] = (f16)in[r][c]; out rows are contiguous 768-f16
// runs so the qkv column permutation costs only index math on the write side.
//   blocks 0..1727        : wqkv  (768x2304 f32 -> [2304][768] f16, perm'd rows)
//   blocks 1728..2303     : wproj (768x768  f32 -> [768][768]  f16, identity)
//   block  2304           : both bias vectors
__global__ __launch_bounds__(256) void pre_k(
    const float* __restrict__ wq, f16* __restrict__ wqT,
    const float* __restrict__ wp, f16* __restrict__ wpT,
    const float* __restrict__ bq_in, float* __restrict__ bq_out,
    const float* __restrict__ bp_in, float* __restrict__ bp_out)
{
  __shared__ float t[32][33];                // +1 pad: conflict-free column reads
  const int bid = blockIdx.x;
  const int tx = threadIdx.x & 31, ty = threadIdx.x >> 5;
  if (bid < 1728 + 576) {
    const float* in; f16* out; int C, ct, rt; bool qkv;
    if (bid < 1728) { in = wq; out = wqT; C = QKV_COLS;
                      ct = (bid % 72) * 32; rt = (bid / 72) * 32; qkv = true; }
    else            { const int b2 = bid - 1728; in = wp; out = wpT; C = EMB;
                      ct = (b2 % 24) * 32; rt = (b2 / 24) * 32; qkv = false; }
#pragma unroll
    for (int p = 0; p < 4; p++)              // coalesced f32 reads along the row
      t[p * 8 + ty][tx] = in[(size_t)(rt + p * 8 + ty) * C + ct + tx];
    __syncthreads();
#pragma unroll
    for (int p = 0; p < 4; p++) {            // coalesced f16 writes along out row
      const int c = ct + p * 8 + ty;
      int colp;
      if (qkv) { const int h = c / 288, rem = c - h * 288, d = rem / 3, s = rem - d * 3;
                 colp = s * 768 + h * 96 + d; }
      else     colp = c;
      out[(size_t)colp * EMB + rt + tx] = (f16)t[tx][p * 8 + ty];
    }
  } else {
    for (int i = threadIdx.x; i < QKV_COLS; i += 256) {
      const int s = i / 768, rem = i - s * 768, h = rem / 96, d = rem - h * 96;
      bq_out[i] = bq_in[h * 288 + d * 3 + s];
    }
    for (int i = threadIdx.x; i < EMB; i += 256) bp_out[i] = bp_in[i];
  }
}

// ---------------- bt-GEMM: C[M,N] = A[M,K] @ Bt[N,K]^T + bias ----------------
// MODE 0: fp32 store to Cout [M,N], A row-major [M][Kd]
// MODE 1 (permuted qkv): tile_n < 1536 -> QK[row][1536] direct (coalesced);
//                        tile_n >= 1536 -> V: LDS transpose -> Vt[bh][d][n] coalesced
// MODE 2: like MODE 0 but A is head-major [b*8+h][2048][96]; k -> (h = k/96, d = k%96).
//         32-wide k-chunks never straddle heads (96 = 3*32), so h = k0/96 per chunk.
// r15: XCD-aware block swizzle (T1): grids are 1152/384 blocks (%8==0), so
// new_lin = (lin&7)*chunk + lin>>3 is bijective; each XCD then owns contiguous
// M-tiles -> A-panel reuse in its private L2 (A re-fetch 8x -> 1x per XCD).
template<int MODE>
__global__ __launch_bounds__(256) void gemm_bt(
    const f16* __restrict__ A, const f16* __restrict__ Bt,
    const float* __restrict__ bias, float* __restrict__ Cout,
    f16* __restrict__ QK, f16* __restrict__ Vt,
    int M, int N, int Kd)
{
  __shared__ f16 smem[MODE == 1 ? 17408 : 8192];   // sA[4096]+sB[4096]; V-epilogue reuses as sT[128][136]
  f16* sA = smem;
  f16* sB = smem + 4096;
  const int tid  = threadIdx.x;
  const int wave = tid >> 6, lane = tid & 63;
  const int quad = lane >> 4, l16 = lane & 15;
  int lin = blockIdx.y * gridDim.x + blockIdx.x;
  {
    const int nwg = gridDim.x * gridDim.y;
    if ((nwg & 7) == 0) {
      const int chunk = nwg >> 3;
      lin = (lin & 7) * chunk + (lin >> 3);
    }
  }
  const int tile_m = (lin / gridDim.x) * 128, tile_n = (lin % gridDim.x) * 128;
  const int wm = (wave >> 1) * 64, wn = (wave & 1) * 64;

  f32x4 acc[4][4];
  for (int i = 0; i < 4; i++)
    for (int j = 0; j < 4; j++)
      acc[i][j] = f32x4{0.f, 0.f, 0.f, 0.f};

  for (int k0 = 0; k0 < Kd; k0 += 32) {
    __syncthreads();
#pragma unroll
    for (int it = 0; it < 2; it++) {
      const int ch  = (it * 4 + wave) * 64 + lane;   // 0..511
      const int row = ch >> 2, c8 = (ch & 3) * 8;
      if (MODE == 2) {
        const int grow = tile_m + row;
        const int bb = grow >> 11, n = grow & 2047;
        const int hh = k0 / 96, d0 = k0 - hh * 96 + c8;
        gl_lds16(A + ((size_t)(bb * NHEADS + hh) * SEQ + n) * HDIM + d0,
                 &sA[(it * 4 + wave) * 512]);
      } else {
        gl_lds16(A + (size_t)(tile_m + row) * Kd + k0 + c8, &sA[(it * 4 + wave) * 512]);
      }
      gl_lds16(Bt + (size_t)(tile_n + row) * Kd + k0 + c8, &sB[(it * 4 + wave) * 512]);
    }
    __syncthreads();

    f16x8 af[4], bfr[4];
    for (int i = 0; i < 4; i++) af[i]  = *(const f16x8*)&sA[(wm + i * 16 + l16) * 32 + quad * 8];
    for (int j = 0; j < 4; j++) bfr[j] = *(const f16x8*)&sB[(wn + j * 16 + l16) * 32 + quad * 8];
    for (int i = 0; i < 4; i++)
      for (int j = 0; j < 4; j++)
        acc[i][j] = __builtin_amdgcn_mfma_f32_16x16x32_f16(af[i], bfr[j], acc[i][j], 0, 0, 0);
  }

  // epilogue: C layout col=lane&15, row=quad*4+reg
  if (MODE == 1 && tile_n >= 1536) {
    // ---- V tile: LDS transpose then coalesced Vt writes ----
    __syncthreads();   // sA/sB dead, safe to overwrite
    f16* sT = smem;    // [128][136]
    for (int j = 0; j < 4; j++) {
      const int cl = wn + j * 16 + l16;
      const float bv = bias[tile_n + cl];
      for (int i = 0; i < 4; i++)
        for (int r = 0; r < 4; r++)
          sT[cl * 136 + wm + i * 16 + quad * 4 + r] = (f16)(acc[i][j][r] + bv);
    }
    __syncthreads();
    const int bb = tile_m >> 11;          // group-local batch
    const int n0 = tile_m & 2047;
#pragma unroll
    for (int l = 0; l < 8; l++) {
      const int cc = l * 256 + tid;       // 0..2047 chunks of 8 f16
      const int rh = cc >> 4, nof = (cc & 15) * 8;
      const int hd = (tile_n - 1536) + rh;
      const int h = hd / 96, d = hd - h * 96;
      f16x8 v = *(const f16x8*)&sT[rh * 136 + nof];
      *(f16x8*)(Vt + ((size_t)(bb * NHEADS + h) * HDIM + d) * SEQ + n0 + nof) = v;
    }
  } else {
    for (int j = 0; j < 4; j++) {
      const int col = tile_n + wn + j * 16 + l16;
      const float bv = bias[col];
      for (int i = 0; i < 4; i++) {
        for (int r = 0; r < 4; r++) {
          const int row = tile_m + wm + i * 16 + quad * 4 + r;
          const float fv = acc[i][j][r] + bv;
          if (MODE != 1) Cout[(size_t)row * N + col] = fv;
          else           QK  [(size_t)row * 1536 + col] = (f16)fv;  // Q cols 0..767, K 768..1535
        }
      }
    }
  }
}

// ---------------- flash attention ----------------
// r14-proven (123 us), byte-identical this round:
//   defer-max (T13, THR=8), deferred l-sum, async staggered K/V staging
//   (gl_lds, source-swizzled, counted vmcnt(6), raw barriers), XCD swizzle,
//   head-major Out, two 64-k sP halves.
//   sK[128][96]: 16B-unit rotation  phys = (u + row) % 12
//   sV[96][128]: 16B-unit XOR       phys = u ^ (d & 15)
//   sP[128][64]: 16B-unit XOR       phys = u ^ (row & 7)
__global__ __launch_bounds__(256, 2) void attn_k(
    const f16* __restrict__ QK, const f16* __restrict__ Vt,
    f16* __restrict__ Out /* [nb*8][2048][96] f16 */, int nbh)
{
  __shared__ f16 sK[128 * 96];
  __shared__ f16 sV[96 * 128];
  __shared__ f16 sP[128 * 64];
  const int tid  = threadIdx.x;
  const int wave = tid >> 6, lane = tid & 63;
  const int quad = lane >> 4, l16 = lane & 15;

  const int bid = blockIdx.x;
  const int xcd = bid & 7, idx = bid >> 3;   // dispatch round-robins XCDs on bid%8
  const int bh  = xcd * (nbh >> 3) + (idx >> 4);
  const int qt  = idx & 15;
  const int b = bh >> 3, h = bh & 7;

  const int wrow = wave * 32;                // this wave's q-row base (32 rows, ti=2)

  const f16* Qb = QK + (size_t)(b * SEQ + qt * 128 + wrow) * 1536 + h * 96;
  const f16* Kb = QK + (size_t)(b * SEQ) * 1536 + 768 + h * 96;
  const f16* Vb = Vt + (size_t)bh * HDIM * SEQ;

  // per-thread pre-swizzled staging source offsets (chunk ck = i*256 + tid):
  //  K: (krow,pu) -> src krow*1536 + ((pu - krow) mod 12)*8 ; dest linear ck*8
  //  V: (vd,pu)   -> src vd*SEQ + (pv ^ (vd&15))*8          ; dest linear ck*8
  int koff[6], voff[6];
#pragma unroll
  for (int i = 0; i < 6; i++) {
    const int ck = i * 256 + tid;
    const int krow = ck / 12, pu = ck - krow * 12;
    const int u = (pu + 12 - krow % 12) % 12;
    koff[i] = krow * 1536 + u * 8;
    const int vd = ck >> 4, pv = ck & 15;
    voff[i] = vd * SEQ + (pv ^ (vd & 15)) * 8;
  }

  f16x8 qf[2][3];
#pragma unroll
  for (int ti = 0; ti < 2; ti++)
#pragma unroll
    for (int kc = 0; kc < 3; kc++)
      qf[ti][kc] = *(const f16x8*)(Qb + (size_t)(ti * 16 + l16) * 1536 + kc * 32 + quad * 8);

  f32x4 oacc[2][6];
#pragma unroll
  for (int ti = 0; ti < 2; ti++)
#pragma unroll
    for (int dj = 0; dj < 6; dj++)
      oacc[ti][dj] = f32x4{0.f, 0.f, 0.f, 0.f};
  f32x4 m_run[2], l_run[2];
#pragma unroll
  for (int ti = 0; ti < 2; ti++) {
    m_run[ti] = f32x4{-1e30f, -1e30f, -1e30f, -1e30f};
    l_run[ti] = f32x4{0.f, 0.f, 0.f, 0.f};   // PER-LANE partial until final reduce
  }

  // prologue: issue K(0) then V(0) (order matters for vmcnt counting)
  {
#pragma unroll
    for (int i = 0; i < 6; i++) gl_lds16(Kb + koff[i], &sK[(i * 256 + wave * 64) * 8]);
#pragma unroll
    for (int i = 0; i < 6; i++) gl_lds16(Vb + voff[i], &sV[(i * 256 + wave * 64) * 8]);
  }

  const int NT = SEQ / 128;
  for (int kt = 0; kt < NT; kt++) {
    // #1: drain K(kt) (kt=0: drain everything incl. qf to make counts exact)
    if (kt == 0) asm volatile("s_waitcnt vmcnt(0)" ::: "memory");
    else         asm volatile("s_waitcnt vmcnt(6)" ::: "memory");
    __builtin_amdgcn_s_barrier();            // #2: sK(kt) visible to all waves
    __builtin_amdgcn_sched_barrier(0);

    // ---- QK^T: each kf read feeds both ti MFMAs ----
    f32x4 sacc[2][8];
#pragma unroll
    for (int ti = 0; ti < 2; ti++)
#pragma unroll
      for (int j = 0; j < 8; j++)
        sacc[ti][j] = f32x4{0.f, 0.f, 0.f, 0.f};
#pragma unroll
    for (int kc = 0; kc < 3; kc++) {
#pragma unroll
      for (int j = 0; j < 8; j++) {
        const int krow = j * 16 + l16;
        const f16x8 kf = *(const f16x8*)&sK[krow * 96 + ((kc * 4 + quad + krow) % 12) * 8];
        sacc[0][j] = __builtin_amdgcn_mfma_f32_16x16x32_f16(qf[0][kc], kf, sacc[0][j], 0, 0, 0);
        sacc[1][j] = __builtin_amdgcn_mfma_f32_16x16x32_f16(qf[1][kc], kf, sacc[1][j], 0, 0, 0);
      }
    }

    __builtin_amdgcn_sched_barrier(0);
    __builtin_amdgcn_s_barrier();            // #3: all waves done reading sK
    if (kt < NT - 1) {                       // issue K(kt+1) -> flies during softmax+PV
      const f16* kb = Kb + (size_t)((kt + 1) * 128) * 1536;
#pragma unroll
      for (int i = 0; i < 6; i++) gl_lds16(kb + koff[i], &sK[(i * 256 + wave * 64) * 8]);
    }
    __builtin_amdgcn_sched_barrier(0);

    // ---- stats per ti: defer-max (skip butterfly+rescale when max didn't grow) ----
    f32x4 rsv[2];
#pragma unroll
    for (int ti = 0; ti < 2; ti++) {
      f32x4 vmx = sacc[ti][0];
#pragma unroll
      for (int j = 1; j < 8; j++) vmx = vmax4(vmx, sacc[ti][j]);
      const int ok = __all(vmx[0] <= m_run[ti][0] + 8.f &&
                           vmx[1] <= m_run[ti][1] + 8.f &&
                           vmx[2] <= m_run[ti][2] + 8.f &&
                           vmx[3] <= m_run[ti][3] + 8.f);
      if (!ok) {
        for (int m = 1; m < 16; m <<= 1) vmx = vmax4(vmx, shflx4(vmx, m));
        const f32x4 nm = vmax4(m_run[ti], vmx);
        f32x4 alpha;
        alpha[0] = __expf(m_run[ti][0] - nm[0]); alpha[1] = __expf(m_run[ti][1] - nm[1]);
        alpha[2] = __expf(m_run[ti][2] - nm[2]); alpha[3] = __expf(m_run[ti][3] - nm[3]);
        m_run[ti] = nm;
        l_run[ti] *= alpha;                  // per-lane partial, alpha row-uniform
#pragma unroll
        for (int dj = 0; dj < 6; dj++) oacc[ti][dj] *= alpha;
      }
      rsv[ti] = f32x4{0.f, 0.f, 0.f, 0.f};
    }

    // #4: drain V(kt) (last iter: nothing newer outstanding -> 0)
    if (kt < NT - 1) asm volatile("s_waitcnt vmcnt(6)" ::: "memory");
    else             asm volatile("s_waitcnt vmcnt(0)" ::: "memory");
    __builtin_amdgcn_s_barrier();            // #5: sV(kt) visible to all waves
    __builtin_amdgcn_sched_barrier(0);

    // ---- two 64-k halves: write P (XOR-swizzled sP) -> PV (vf read feeds both ti) ----
#pragma unroll
    for (int c2 = 0; c2 < 2; c2++) {
#pragma unroll
      for (int ti = 0; ti < 2; ti++) {
        const int prow = wrow + ti * 16 + quad * 4;
#pragma unroll
        for (int jl = 0; jl < 4; jl++) {
          const int j = c2 * 4 + jl;
          f32x4 p;
          p[0] = __expf(sacc[ti][j][0] - m_run[ti][0]);
          p[1] = __expf(sacc[ti][j][1] - m_run[ti][1]);
          p[2] = __expf(sacc[ti][j][2] - m_run[ti][2]);
          p[3] = __expf(sacc[ti][j][3] - m_run[ti][3]);
          rsv[ti] += p;
          const int unit = jl * 2 + (l16 >> 3);   // 16B unit of col = jl*16+l16
          const int within = l16 & 7;
#pragma unroll
          for (int rr = 0; rr < 4; rr++) {
            const int row = prow + rr;
            sP[row * 64 + (unit ^ (row & 7)) * 8 + within] = (f16)p[rr];
          }
        }
      }
#pragma unroll
      for (int kc2 = 0; kc2 < 2; kc2++) {
        const f16x8 pf0 = *(const f16x8*)&sP[(wrow + l16) * 64
                                            + ((kc2 * 4 + quad) ^ (l16 & 7)) * 8];
        const f16x8 pf1 = *(const f16x8*)&sP[(wrow + 16 + l16) * 64
                                            + ((kc2 * 4 + quad) ^ (l16 & 7)) * 8];
#pragma unroll
        for (int dj = 0; dj < 6; dj++) {
          const int vph = (c2 * 8 + kc2 * 4 + quad) ^ l16;   // d&15 == l16
          const f16x8 vf = *(const f16x8*)&sV[(dj * 16 + l16) * 128 + vph * 8];
          oacc[0][dj] = __builtin_amdgcn_mfma_f32_16x16x32_f16(pf0, vf, oacc[0][dj], 0, 0, 0);
          oacc[1][dj] = __builtin_amdgcn_mfma_f32_16x16x32_f16(pf1, vf, oacc[1][dj], 0, 0, 0);
        }
      }
    }

    __builtin_amdgcn_sched_barrier(0);
    __builtin_amdgcn_s_barrier();            // #6: all waves done reading sV
    if (kt < NT - 1) {                       // issue V(kt+1) -> flies through next QK^T
      const f16* vb = Vb + (kt + 1) * 128;
#pragma unroll
      for (int i = 0; i < 6; i++) gl_lds16(vb + voff[i], &sV[(i * 256 + wave * 64) * 8]);
    }
    __builtin_amdgcn_sched_barrier(0);

    // ---- accumulate per-lane partial sums (NO butterfly here) ----
#pragma unroll
    for (int ti = 0; ti < 2; ti++) l_run[ti] += rsv[ti];
  }

  // ---- single deferred row-sum reduction (32 bpermutes total) ----
#pragma unroll
  for (int ti = 0; ti < 2; ti++)
    for (int m = 1; m < 16; m <<= 1) l_run[ti] += shflx4(l_run[ti], m);

  const float inv_scale = 0.10206207261596577f;  // 1/sqrt(96), applied AFTER softmax per ref
#pragma unroll
  for (int ti = 0; ti < 2; ti++) {
#pragma unroll
    for (int r = 0; r < 4; r++) {
      const int qrow = qt * 128 + wrow + ti * 16 + quad * 4 + r;
      const float invl = inv_scale / l_run[ti][r];
      const size_t base = ((size_t)bh * SEQ + qrow) * HDIM;   // head-major out
#pragma unroll
      for (int dj = 0; dj < 6; dj++)
        Out[base + dj * 16 + l16] = (f16)(oacc[ti][dj][r] * invl);
    }
  }
}

// ---------------- launch ----------------
extern "C" void kernel_launch(void* const* d_in, const int* in_sizes, int n_in,
                              void* d_out, int out_size, void* d_ws, size_t ws_size,
                              hipStream_t stream) {
  const float* x      = (const float*)d_in[0];
  const float* w_qkv  = (const float*)d_in[1];
  const float* b_qkv  = (const float*)d_in[2];
  const float* w_proj = (const float*)d_in[3];
  const float* b_proj = (const float*)d_in[4];
  float* outF = (float*)d_out;   // fp32 output

  const size_t fixed = 256 + (size_t)QKV_COLS * EMB * 2 + (size_t)EMB * EMB * 2
                     + QKV_COLS * 4 + EMB * 4 + 256;
  const size_t perb = (size_t)4 * PB * 2;  // QK(2) + Vt(1) + attn(1) per batch, in PB units
  int nb = (ws_size >= fixed + 4 * perb) ? 4 : (ws_size >= fixed + 2 * perb) ? 2 : 1;

  char* ws = (char*)d_ws;
  ws += 256;
  f16*   wqkvT  = (f16*)ws;   ws += (size_t)QKV_COLS * EMB * 2;
  f16*   wprojT = (f16*)ws;   ws += (size_t)EMB * EMB * 2;
  float* bq     = (float*)ws; ws += (size_t)QKV_COLS * 4;
  float* bp     = (float*)ws; ws += (size_t)EMB * 4 + 256;
  f16* QK   = (f16*)ws;       ws += (size_t)nb * 2 * PB * 2;   // [nb*2048][1536]
  f16* Vt   = (f16*)ws;       ws += (size_t)nb * PB * 2;       // [nb*8][96][2048]
  f16* attn = (f16*)ws;       ws += (size_t)nb * PB * 2;       // [nb*8][2048][96] head-major

  pre_k<<<1728 + 576 + 1, 256, 0, stream>>>(w_qkv, wqkvT, w_proj, wprojT,
                                            b_qkv, bq, b_proj, bp);

  for (int outer = 0; outer < BATCH / nb; outer++) {
    const int bbase = outer * nb;
    const size_t goff = (size_t)bbase * PB;
    f16* xg = (f16*)(outF + goff);           // stage f16 x inside fp32 out region (dead before proj)
    const int n8 = (int)((size_t)nb * PB / 8);
    conv_x8_k<<<(n8 + 255) / 256, 256, 0, stream>>>(x, goff, xg, n8);

    dim3 g1(QKV_COLS / 128, nb * SEQ / 128);
    gemm_bt<1><<<g1, 256, 0, stream>>>(xg, wqkvT, bq, nullptr, QK, Vt,
                                       nb * SEQ, QKV_COLS, EMB);

    attn_k<<<dim3(16 * nb * NHEADS), 256, 0, stream>>>(QK, Vt, attn, nb * NHEADS);

    dim3 g3(EMB / 128, nb * SEQ / 128);
    gemm_bt<2><<<g3, 256, 0, stream>>>(attn, wprojT, bp, outF + goff,
                                       nullptr, nullptr,
                                       nb * SEQ, EMB, EMB);
  }
}

// Round 16
// 278.814 us; speedup vs baseline: 1.9531x; 1.0414x over previous
//
#include <hip/hip_runtime.h>
#include <hip/hip_bf16.h>

#define EMB 768
#define NHEADS 8
#define HDIM 96
#define SEQ 2048
#define BATCH 4
#define QKV_COLS 2304
#define PB ((size_t)SEQ * EMB)   // per-batch elements

typedef _Float16 f16;
typedef _Float16 f16x8 __attribute__((ext_vector_type(8)));
typedef float f32x4 __attribute__((ext_vector_type(4)));

__device__ __forceinline__ void gl_lds16(const f16* g, f16* l) {
  __builtin_amdgcn_global_load_lds((const __attribute__((address_space(1))) void*)g,
                                   (__attribute__((address_space(3))) void*)l, 16, 0, 0);
}
__device__ __forceinline__ f32x4 shflx4(f32x4 v, int m) {
  f32x4 r;
  r[0] = __shfl_xor(v[0], m); r[1] = __shfl_xor(v[1], m);
  r[2] = __shfl_xor(v[2], m); r[3] = __shfl_xor(v[3], m);
  return r;
}
__device__ __forceinline__ f32x4 vmax4(f32x4 a, f32x4 b) {
  f32x4 r;
  r[0] = fmaxf(a[0], b[0]); r[1] = fmaxf(a[1], b[1]);
  r[2] = fmaxf(a[2], b[2]); r[3] = fmaxf(a[3], b[3]);
  return r;
}

// ---------------- conversions ----------------
__global__ __launch_bounds__(256) void conv_x8_k(const float* __restrict__ in, size_t in_off,
                                                 f16* __restrict__ out, int n8) {
  int i = blockIdx.x * 256 + threadIdx.x;
  if (i >= n8) return;
  const float4 a = *(const float4*)(in + in_off + (size_t)i * 8);
  const float4 b = *(const float4*)(in + in_off + (size_t)i * 8 + 4);
  f16x8 o;
  o[0] = (f16)a.x; o[1] = (f16)a.y; o[2] = (f16)a.z; o[3] = (f16)a.w;
  o[4] = (f16)b.x; o[5] = (f16)b.y; o[6] = (f16)b.z; o[7] = (f16)b.w;
  *(f16x8*)(out + (size_t)i * 8) = o;
}

// ---------------- merged weight preprocessing (r15-proven) ----------------
__global__ __launch_bounds__(256) void pre_k(
    const float* __restrict__ wq, f16* __restrict__ wqT,
    const float* __restrict__ wp, f16* __restrict__ wpT,
    const float* __restrict__ bq_in, float* __restrict__ bq_out,
    const float* __restrict__ bp_in, float* __restrict__ bp_out)
{
  __shared__ float t[32][33];                // +1 pad: conflict-free column reads
  const int bid = blockIdx.x;
  const int tx = threadIdx.x & 31, ty = threadIdx.x >> 5;
  if (bid < 1728 + 576) {
    const float* in; f16* out; int C, ct, rt; bool qkv;
    if (bid < 1728) { in = wq; out = wqT; C = QKV_COLS;
                      ct = (bid % 72) * 32; rt = (bid / 72) * 32; qkv = true; }
    else            { const int b2 = bid - 1728; in = wp; out = wpT; C = EMB;
                      ct = (b2 % 24) * 32; rt = (b2 / 24) * 32; qkv = false; }
#pragma unroll
    for (int p = 0; p < 4; p++)              // coalesced f32 reads along the row
      t[p * 8 + ty][tx] = in[(size_t)(rt + p * 8 + ty) * C + ct + tx];
    __syncthreads();
#pragma unroll
    for (int p = 0; p < 4; p++) {            // coalesced f16 writes along out row
      const int c = ct + p * 8 + ty;
      int colp;
      if (qkv) { const int h = c / 288, rem = c - h * 288, d = rem / 3, s = rem - d * 3;
                 colp = s * 768 + h * 96 + d; }
      else     colp = c;
      out[(size_t)colp * EMB + rt + tx] = (f16)t[tx][p * 8 + ty];
    }
  } else {
    for (int i = threadIdx.x; i < QKV_COLS; i += 256) {
      const int s = i / 768, rem = i - s * 768, h = rem / 96, d = rem - h * 96;
      bq_out[i] = bq_in[h * 288 + d * 3 + s];
    }
    for (int i = threadIdx.x; i < EMB; i += 256) bp_out[i] = bp_in[i];
  }
}

// ---------------- bt-GEMM (r15-proven, incl. XCD swizzle) ----------------
template<int MODE>
__global__ __launch_bounds__(256) void gemm_bt(
    const f16* __restrict__ A, const f16* __restrict__ Bt,
    const float* __restrict__ bias, float* __restrict__ Cout,
    f16* __restrict__ QK, f16* __restrict__ Vt,
    int M, int N, int Kd)
{
  __shared__ f16 smem[MODE == 1 ? 17408 : 8192];   // sA[4096]+sB[4096]; V-epilogue reuses as sT[128][136]
  f16* sA = smem;
  f16* sB = smem + 4096;
  const int tid  = threadIdx.x;
  const int wave = tid >> 6, lane = tid & 63;
  const int quad = lane >> 4, l16 = lane & 15;
  int lin = blockIdx.y * gridDim.x + blockIdx.x;
  {
    const int nwg = gridDim.x * gridDim.y;
    if ((nwg & 7) == 0) {
      const int chunk = nwg >> 3;
      lin = (lin & 7) * chunk + (lin >> 3);
    }
  }
  const int tile_m = (lin / gridDim.x) * 128, tile_n = (lin % gridDim.x) * 128;
  const int wm = (wave >> 1) * 64, wn = (wave & 1) * 64;

  f32x4 acc[4][4];
  for (int i = 0; i < 4; i++)
    for (int j = 0; j < 4; j++)
      acc[i][j] = f32x4{0.f, 0.f, 0.f, 0.f};

  for (int k0 = 0; k0 < Kd; k0 += 32) {
    __syncthreads();
#pragma unroll
    for (int it = 0; it < 2; it++) {
      const int ch  = (it * 4 + wave) * 64 + lane;   // 0..511
      const int row = ch >> 2, c8 = (ch & 3) * 8;
      if (MODE == 2) {
        const int grow = tile_m + row;
        const int bb = grow >> 11, n = grow & 2047;
        const int hh = k0 / 96, d0 = k0 - hh * 96 + c8;
        gl_lds16(A + ((size_t)(bb * NHEADS + hh) * SEQ + n) * HDIM + d0,
                 &sA[(it * 4 + wave) * 512]);
      } else {
        gl_lds16(A + (size_t)(tile_m + row) * Kd + k0 + c8, &sA[(it * 4 + wave) * 512]);
      }
      gl_lds16(Bt + (size_t)(tile_n + row) * Kd + k0 + c8, &sB[(it * 4 + wave) * 512]);
    }
    __syncthreads();

    f16x8 af[4], bfr[4];
    for (int i = 0; i < 4; i++) af[i]  = *(const f16x8*)&sA[(wm + i * 16 + l16) * 32 + quad * 8];
    for (int j = 0; j < 4; j++) bfr[j] = *(const f16x8*)&sB[(wn + j * 16 + l16) * 32 + quad * 8];
    for (int i = 0; i < 4; i++)
      for (int j = 0; j < 4; j++)
        acc[i][j] = __builtin_amdgcn_mfma_f32_16x16x32_f16(af[i], bfr[j], acc[i][j], 0, 0, 0);
  }

  // epilogue: C layout col=lane&15, row=quad*4+reg
  if (MODE == 1 && tile_n >= 1536) {
    __syncthreads();   // sA/sB dead, safe to overwrite
    f16* sT = smem;    // [128][136]
    for (int j = 0; j < 4; j++) {
      const int cl = wn + j * 16 + l16;
      const float bv = bias[tile_n + cl];
      for (int i = 0; i < 4; i++)
        for (int r = 0; r < 4; r++)
          sT[cl * 136 + wm + i * 16 + quad * 4 + r] = (f16)(acc[i][j][r] + bv);
    }
    __syncthreads();
    const int bb = tile_m >> 11;          // group-local batch
    const int n0 = tile_m & 2047;
#pragma unroll
    for (int l = 0; l < 8; l++) {
      const int cc = l * 256 + tid;       // 0..2047 chunks of 8 f16
      const int rh = cc >> 4, nof = (cc & 15) * 8;
      const int hd = (tile_n - 1536) + rh;
      const int h = hd / 96, d = hd - h * 96;
      f16x8 v = *(const f16x8*)&sT[rh * 136 + nof];
      *(f16x8*)(Vt + ((size_t)(bb * NHEADS + h) * HDIM + d) * SEQ + n0 + nof) = v;
    }
  } else {
    for (int j = 0; j < 4; j++) {
      const int col = tile_n + wn + j * 16 + l16;
      const float bv = bias[col];
      for (int i = 0; i < 4; i++) {
        for (int r = 0; r < 4; r++) {
          const int row = tile_m + wm + i * 16 + quad * 4 + r;
          const float fv = acc[i][j][r] + bv;
          if (MODE != 1) Cout[(size_t)row * N + col] = fv;
          else           QK  [(size_t)row * 1536 + col] = (f16)fv;  // Q cols 0..767, K 768..1535
        }
      }
    }
  }
}

// ---------------- flash attention (r16: KVBLK=64 + k-split x2 + sP alias) ----------------
// Occupancy package (r12 lesson: capacity AND supply together):
//  - KVBLK 128->64: sK[64][96] 12KB + sV[96][64] 12KB = 24 KB LDS; sacc halves
//    (64->32 VGPR) so VGPR stays <=128.
//  - sP[128][32] ALIASED into sK (8 KB <= 12 KB), r12's correctness-proven
//    3-barrier flow (tiles-ready / alias-guard / overwrite-guard).
//  - k-split x2: block handles kt in [half*16, half*16+16) of 32 KVBLK-64 tiles;
//    r14-proven math (defer-max THR=8 + deferred l-sum) verbatim on the subrange.
//    Partial out: oh = O/l (f16, no inv_scale) + (m,l) f32; exact merge kernel.
//  - grid 32*nbh = 1024 blocks; 24 KB + <=128 VGPR -> 4 blocks/CU = 16 waves/CU,
//    perfectly packed (1024 = 4*256). Was 2 blocks / 8 waves / grid-capped.
// Swizzles (all bijective, write&read same formula):
//   sK: phys unit = (u + krow) % 12 (12 units/row, src-swizzled gl_lds)
//   sV: phys unit = u ^ (vd & 7)    (8 units/row, src-swizzled gl_lds)
//   sP: phys unit = u ^ (row & 3)   (4 units/row)
__global__ __launch_bounds__(256, 2) void attn_k(
    const f16* __restrict__ QK, const f16* __restrict__ Vt,
    f16* __restrict__ oh0, f16* __restrict__ oh1, float* __restrict__ ml,
    int nbh)
{
  __shared__ f16 sK[64 * 96];
  __shared__ f16 sV[96 * 64];
  f16* sP = sK;                              // alias: 128*32 f16 = 8 KB < 12 KB
  const int tid  = threadIdx.x;
  const int wave = tid >> 6, lane = tid & 63;
  const int quad = lane >> 4, l16 = lane & 15;

  const int bid = blockIdx.x;                // 32*nbh blocks
  const int xcd = bid & 7, idx = bid >> 3;
  const int bh  = xcd * (nbh >> 3) + (idx >> 5);
  const int rem = idx & 31;
  const int qt  = rem & 15, half = rem >> 4;
  const int b = bh >> 3, h = bh & 7;
  const int nrows = nbh * SEQ;

  const int wrow = wave * 32;                // wave's q-row base (32 rows, ti=2)

  const f16* Qb = QK + (size_t)(b * SEQ + qt * 128 + wrow) * 1536 + h * 96;
  const f16* Kb = QK + (size_t)(b * SEQ) * 1536 + 768 + h * 96
                + (size_t)(half * 1024) * 1536;          // half's k-range base
  const f16* Vb = Vt + (size_t)bh * HDIM * SEQ + half * 1024;

  // staging source offsets (chunk ck = i*256 + tid, i<3; dest linear ck*8):
  //  K: 64 rows x 12 units: src krow*1536 + ((pu - krow) mod 12)*8
  //  V: 96 rows x  8 units: src vd*SEQ + (pv ^ (vd&7))*8
  int koff[3], voff[3];
#pragma unroll
  for (int i = 0; i < 3; i++) {
    const int ck = i * 256 + tid;
    const int krow = ck / 12, pu = ck - krow * 12;
    const int u = (pu + 12 - krow % 12) % 12;
    koff[i] = krow * 1536 + u * 8;
    const int vd = ck >> 3, pv = ck & 7;
    voff[i] = vd * SEQ + (pv ^ (vd & 7)) * 8;
  }

  f16x8 qf[2][3];
#pragma unroll
  for (int ti = 0; ti < 2; ti++)
#pragma unroll
    for (int kc = 0; kc < 3; kc++)
      qf[ti][kc] = *(const f16x8*)(Qb + (size_t)(ti * 16 + l16) * 1536 + kc * 32 + quad * 8);

  f32x4 oacc[2][6];
#pragma unroll
  for (int ti = 0; ti < 2; ti++)
#pragma unroll
    for (int dj = 0; dj < 6; dj++)
      oacc[ti][dj] = f32x4{0.f, 0.f, 0.f, 0.f};
  f32x4 m_run[2], l_run[2];
#pragma unroll
  for (int ti = 0; ti < 2; ti++) {
    m_run[ti] = f32x4{-1e30f, -1e30f, -1e30f, -1e30f};
    l_run[ti] = f32x4{0.f, 0.f, 0.f, 0.f};   // per-lane partial until final reduce
  }

  // prologue: stage first tile of this half
#pragma unroll
  for (int i = 0; i < 3; i++) gl_lds16(Kb + koff[i], &sK[(i * 256 + wave * 64) * 8]);
#pragma unroll
  for (int i = 0; i < 3; i++) gl_lds16(Vb + voff[i], &sV[(i * 256 + wave * 64) * 8]);

  for (int it = 0; it < 16; it++) {
    // (a) tiles ready
    asm volatile("s_waitcnt vmcnt(0)" ::: "memory");
    __builtin_amdgcn_s_barrier();
    __builtin_amdgcn_sched_barrier(0);

    // ---- QK^T over 64 k (4 j-tiles), each kf feeds both ti ----
    f32x4 sacc[2][4];
#pragma unroll
    for (int ti = 0; ti < 2; ti++)
#pragma unroll
      for (int j = 0; j < 4; j++)
        sacc[ti][j] = f32x4{0.f, 0.f, 0.f, 0.f};
#pragma unroll
    for (int kc = 0; kc < 3; kc++) {
#pragma unroll
      for (int j = 0; j < 4; j++) {
        const int krow = j * 16 + l16;
        const f16x8 kf = *(const f16x8*)&sK[krow * 96 + ((kc * 4 + quad + krow) % 12) * 8];
        sacc[0][j] = __builtin_amdgcn_mfma_f32_16x16x32_f16(qf[0][kc], kf, sacc[0][j], 0, 0, 0);
        sacc[1][j] = __builtin_amdgcn_mfma_f32_16x16x32_f16(qf[1][kc], kf, sacc[1][j], 0, 0, 0);
      }
    }

    // (b) alias guard: all waves done reading sK before P overwrites it
    __builtin_amdgcn_sched_barrier(0);
    __builtin_amdgcn_s_barrier();
    __builtin_amdgcn_sched_barrier(0);

    // ---- stats: defer-max (skip butterfly+rescale when max didn't grow) ----
    f32x4 rsv[2];
#pragma unroll
    for (int ti = 0; ti < 2; ti++) {
      f32x4 vmx = sacc[ti][0];
#pragma unroll
      for (int j = 1; j < 4; j++) vmx = vmax4(vmx, sacc[ti][j]);
      const int ok = __all(vmx[0] <= m_run[ti][0] + 8.f &&
                           vmx[1] <= m_run[ti][1] + 8.f &&
                           vmx[2] <= m_run[ti][2] + 8.f &&
                           vmx[3] <= m_run[ti][3] + 8.f);
      if (!ok) {
        for (int m = 1; m < 16; m <<= 1) vmx = vmax4(vmx, shflx4(vmx, m));
        const f32x4 nm = vmax4(m_run[ti], vmx);
        f32x4 alpha;
        alpha[0] = __expf(m_run[ti][0] - nm[0]); alpha[1] = __expf(m_run[ti][1] - nm[1]);
        alpha[2] = __expf(m_run[ti][2] - nm[2]); alpha[3] = __expf(m_run[ti][3] - nm[3]);
        m_run[ti] = nm;
        l_run[ti] *= alpha;
#pragma unroll
        for (int dj = 0; dj < 6; dj++) oacc[ti][dj] *= alpha;
      }
      rsv[ti] = f32x4{0.f, 0.f, 0.f, 0.f};
    }

    // ---- two 32-k halves: write P (sP=sK alias) -> PV (vf feeds both ti) ----
#pragma unroll
    for (int c2 = 0; c2 < 2; c2++) {
#pragma unroll
      for (int ti = 0; ti < 2; ti++) {
        const int prow = wrow + ti * 16 + quad * 4;
#pragma unroll
        for (int jl = 0; jl < 2; jl++) {
          const int j = c2 * 2 + jl;
          f32x4 p;
          p[0] = __expf(sacc[ti][j][0] - m_run[ti][0]);
          p[1] = __expf(sacc[ti][j][1] - m_run[ti][1]);
          p[2] = __expf(sacc[ti][j][2] - m_run[ti][2]);
          p[3] = __expf(sacc[ti][j][3] - m_run[ti][3]);
          rsv[ti] += p;
          const int unit = jl * 2 + (l16 >> 3);   // 16B unit of col = jl*16+l16
          const int within = l16 & 7;
#pragma unroll
          for (int rr = 0; rr < 4; rr++) {
            const int row = prow + rr;
            sP[row * 32 + (unit ^ (row & 3)) * 8 + within] = (f16)p[rr];
          }
        }
      }
#pragma unroll
      for (int ti = 0; ti < 2; ti++) {
        const int prw = wrow + ti * 16 + l16;
        const f16x8 pf = *(const f16x8*)&sP[prw * 32 + (quad ^ (l16 & 3)) * 8];
#pragma unroll
        for (int dj = 0; dj < 6; dj++) {
          const int vph = (c2 * 4 + quad) ^ (l16 & 7);
          const f16x8 vf = *(const f16x8*)&sV[(dj * 16 + l16) * 64 + vph * 8];
          oacc[ti][dj] = __builtin_amdgcn_mfma_f32_16x16x32_f16(pf, vf, oacc[ti][dj], 0, 0, 0);
        }
      }
    }

    // (c) overwrite guard: all waves done with sP & sV -> stage next tile
    __builtin_amdgcn_sched_barrier(0);
    __builtin_amdgcn_s_barrier();
    if (it < 15) {
      const f16* kb = Kb + (size_t)((it + 1) * 64) * 1536;
      const f16* vb = Vb + (it + 1) * 64;
#pragma unroll
      for (int i = 0; i < 3; i++) gl_lds16(kb + koff[i], &sK[(i * 256 + wave * 64) * 8]);
#pragma unroll
      for (int i = 0; i < 3; i++) gl_lds16(vb + voff[i], &sV[(i * 256 + wave * 64) * 8]);
    }
    __builtin_amdgcn_sched_barrier(0);

    // ---- accumulate per-lane partial sums (registers; overlaps staging) ----
#pragma unroll
    for (int ti = 0; ti < 2; ti++) l_run[ti] += rsv[ti];
  }

  // ---- single deferred row-sum reduction ----
#pragma unroll
  for (int ti = 0; ti < 2; ti++)
    for (int m = 1; m < 16; m <<= 1) l_run[ti] += shflx4(l_run[ti], m);

  // ---- partial epilogue: oh = O/l (NO inv_scale; applied in merge), m/l f32 ----
  f16* oh = half ? oh1 : oh0;
#pragma unroll
  for (int ti = 0; ti < 2; ti++) {
#pragma unroll
    for (int r = 0; r < 4; r++) {
      const int qrow = qt * 128 + wrow + ti * 16 + quad * 4 + r;
      const float invl = 1.f / l_run[ti][r];
      const size_t rowg = (size_t)bh * SEQ + qrow;
#pragma unroll
      for (int dj = 0; dj < 6; dj++)
        oh[rowg * 96 + dj * 16 + l16] = (f16)(oacc[ti][dj][r] * invl);
      if (l16 == 0) {
        ml[((size_t)half * nrows + rowg) * 2 + 0] = m_run[ti][r];
        ml[((size_t)half * nrows + rowg) * 2 + 1] = l_run[ti][r];
      }
    }
  }
}

// ---------------- flash merge: out = inv_scale*(w0*oh0 + w1*oh1)/(w0+w1) ----------------
// w_h = exp(m_h - max(m0,m1)) * l_h  (exact regardless of defer-max: pure algebra).
// out aliases oh0's buffer: each thread reads both inputs then writes -> safe.
__global__ __launch_bounds__(256) void merge_k(
    const f16* __restrict__ oh0_, const f16* __restrict__ oh1,
    const float* __restrict__ ml, f16* __restrict__ out,
    int nchunks, int nrows)
{
  const int t = blockIdx.x * 256 + threadIdx.x;
  if (t >= nchunks) return;
  const int row = t / 12, off = (t - row * 12) * 8;
  const float m0 = ml[(size_t)row * 2 + 0], l0 = ml[(size_t)row * 2 + 1];
  const float m1 = ml[((size_t)nrows + row) * 2 + 0], l1 = ml[((size_t)nrows + row) * 2 + 1];
  const float nm = fmaxf(m0, m1);
  const float w0 = __expf(m0 - nm) * l0, w1 = __expf(m1 - nm) * l1;
  const float s = 0.10206207261596577f / (w0 + w1);   // 1/sqrt(96) post-softmax per ref
  const f16x8 a = *(const f16x8*)(oh0_ + (size_t)row * 96 + off);
  const f16x8 bvv = *(const f16x8*)(oh1 + (size_t)row * 96 + off);
  f16x8 o;
#pragma unroll
  for (int j = 0; j < 8; j++)
    o[j] = (f16)((w0 * (float)a[j] + w1 * (float)bvv[j]) * s);
  *(f16x8*)(out + (size_t)row * 96 + off) = o;
}

// ---------------- launch ----------------
extern "C" void kernel_launch(void* const* d_in, const int* in_sizes, int n_in,
                              void* d_out, int out_size, void* d_ws, size_t ws_size,
                              hipStream_t stream) {
  const float* x      = (const float*)d_in[0];
  const float* w_qkv  = (const float*)d_in[1];
  const float* b_qkv  = (const float*)d_in[2];
  const float* w_proj = (const float*)d_in[3];
  const float* b_proj = (const float*)d_in[4];
  float* outF = (float*)d_out;   // fp32 output

  const size_t fixed = 256 + (size_t)QKV_COLS * EMB * 2 + (size_t)EMB * EMB * 2
                     + QKV_COLS * 4 + EMB * 4 + 256;
  const size_t perb = (size_t)4 * PB * 2;  // QK(2) + Vt(1) + attn(1) per batch, in PB units
  int nb = (ws_size >= fixed + 4 * perb) ? 4 : (ws_size >= fixed + 2 * perb) ? 2 : 1;

  char* ws = (char*)d_ws;
  ws += 256;
  f16*   wqkvT  = (f16*)ws;   ws += (size_t)QKV_COLS * EMB * 2;
  f16*   wprojT = (f16*)ws;   ws += (size_t)EMB * EMB * 2;
  float* bq     = (float*)ws; ws += (size_t)QKV_COLS * 4;
  float* bp     = (float*)ws; ws += (size_t)EMB * 4 + 256;
  f16* QK   = (f16*)ws;       ws += (size_t)nb * 2 * PB * 2;   // [nb*2048][1536]
  f16* Vt   = (f16*)ws;       ws += (size_t)nb * PB * 2;       // [nb*8][96][2048]
  f16* attn = (f16*)ws;       ws += (size_t)nb * PB * 2;       // [nb*8][2048][96] head-major (oh0 + merged)

  pre_k<<<1728 + 576 + 1, 256, 0, stream>>>(w_qkv, wqkvT, w_proj, wprojT,
                                            b_qkv, bq, b_proj, bp);

  for (int outer = 0; outer < BATCH / nb; outer++) {
    const int bbase = outer * nb;
    const size_t goff = (size_t)bbase * PB;
    const int nbh = nb * NHEADS;
    const int nrows = nbh * SEQ;
    // outF+goff region (nb*PB floats) triple-duty scratch:
    //   [0, nb*PB*2)B   : xg (f16 staged x; dead after gemm1) then oh1 partial
    //   [nb*PB*2, +1MB) : ml partials [2][nrows][2] f32
    f16* xg = (f16*)(outF + goff);
    f16* oh1 = (f16*)(outF + goff);
    float* ml = (float*)((char*)(outF + goff) + (size_t)nb * PB * 2);
    const int n8 = (int)((size_t)nb * PB / 8);
    conv_x8_k<<<(n8 + 255) / 256, 256, 0, stream>>>(x, goff, xg, n8);

    dim3 g1(QKV_COLS / 128, nb * SEQ / 128);
    gemm_bt<1><<<g1, 256, 0, stream>>>(xg, wqkvT, bq, nullptr, QK, Vt,
                                       nb * SEQ, QKV_COLS, EMB);

    attn_k<<<dim3(32 * nbh), 256, 0, stream>>>(QK, Vt, attn, oh1, ml, nbh);

    const int nchunks = nrows * 12;
    merge_k<<<(nchunks + 255) / 256, 256, 0, stream>>>(attn, oh1, ml, attn,
                                                       nchunks, nrows);

    dim3 g3(EMB / 128, nb * SEQ / 128);
    gemm_bt<2><<<g3, 256, 0, stream>>>(attn, wprojT, bp, outF + goff,
                                       nullptr, nullptr,
                                       nb * SEQ, EMB, EMB);
  }
}